// Round 18
// baseline (2772.881 us; speedup 1.0000x reference)
//
#include <hip/hip_runtime.h>

#define TOKENS   32768
#define DIM      256
#define KCB      1024
#define CBOOKS   8
#define NTOK     2048
#define ZQ_ELEMS (TOKENS * DIM)
#define EPS_GAP  2.0e-2f

typedef _Float16 f16x8 __attribute__((ext_vector_type(8)));
typedef float    f32x4 __attribute__((ext_vector_type(4)));

// ---------------------------------------------------------------------------
// numpy pairwise sum of squares (verified bit-exact, r6).
// ---------------------------------------------------------------------------
__device__ float np_pairwise_sumsq_256(const float4* a4) {
  #pragma clang fp contract(off)
  float h[2];
  for (int hh = 0; hh < 2; ++hh) {
    const float4* b = a4 + hh * 32;
    float4 v0 = b[0], v1 = b[1];
    float r0 = v0.x * v0.x, r1 = v0.y * v0.y, r2 = v0.z * v0.z, r3 = v0.w * v0.w;
    float r4 = v1.x * v1.x, r5 = v1.y * v1.y, r6 = v1.z * v1.z, r7 = v1.w * v1.w;
    for (int t = 1; t < 16; ++t) {
      float4 w0 = b[2 * t], w1 = b[2 * t + 1];
      r0 = r0 + w0.x * w0.x; r1 = r1 + w0.y * w0.y;
      r2 = r2 + w0.z * w0.z; r3 = r3 + w0.w * w0.w;
      r4 = r4 + w1.x * w1.x; r5 = r5 + w1.y * w1.y;
      r6 = r6 + w1.z * w1.z; r7 = r7 + w1.w * w1.w;
    }
    h[hh] = ((r0 + r1) + (r2 + r3)) + ((r4 + r5) + (r6 + r7));
  }
  return h[0] + h[1];
}

__device__ __forceinline__ float4 f4_muladd(float4 a, float4 b, float4 c) {
  #pragma clang fp contract(off)
  float4 r;
  r.x = a.x * b.x + c.x;
  r.y = a.y * b.y + c.y;
  r.z = a.z * b.z + c.z;
  r.w = a.w * b.w + c.w;
  return r;
}

__global__ __launch_bounds__(256) void rvq_norms_kernel(
    const float* __restrict__ cb, float* __restrict__ sume) {
  int row = blockIdx.x * 256 + threadIdx.x;
  sume[row] = np_pairwise_sumsq_256((const float4*)&cb[(size_t)row * DIM]);
}

// ---------------------------------------------------------------------------
// Prepack ONE codebook into fragment-linear fp16 hi/lo (r16-verified layout).
// Also zeroes the fixup counter (separate dispatch -> no race with screen).
// ---------------------------------------------------------------------------
__global__ __launch_bounds__(256) void rvq_efsplit_kernel(
    const float* __restrict__ cbc, f16x8* __restrict__ EfC,
    int* __restrict__ fix_cnt) {
  if (blockIdx.x == 0 && threadIdx.x == 0) *fix_cnt = 0;
  int gw = blockIdx.x * 4 + (threadIdx.x >> 6);   // nfrag 0..63
  int l  = threadIdx.x & 63;
  int row = gw * 16 + (l & 15);
  #pragma unroll
  for (int kb = 0; kb < 8; ++kb) {
    int d0 = kb * 32 + ((l >> 4) << 3);
    float4 u = *(const float4*)&cbc[(size_t)row * DIM + d0];
    float4 v = *(const float4*)&cbc[(size_t)row * DIM + d0 + 4];
    float ev[8] = {u.x, u.y, u.z, u.w, v.x, v.y, v.z, v.w};
    f16x8 hi, lo;
    #pragma unroll
    for (int i = 0; i < 8; ++i) {
      _Float16 h = (_Float16)ev[i];
      hi[i] = h; lo[i] = (_Float16)(ev[i] - (float)h);
    }
    EfC[((size_t)gw * 16 + kb) * 64 + l]     = hi;
    EfC[((size_t)gw * 16 + kb + 8) * 64 + l] = lo;
  }
}

// ---------------------------------------------------------------------------
// MFMA screen v4: 512 blocks x 128 thr (2 waves). Wave owns 32 tokens
// (TWO 16x16 A fragments, full K in registers -> each B LDS read feeds
// 6 MFMAs instead of 3; total ds_read_b128 halved vs r17, which was the
// measured bottleneck). B staged per (ntile,kc) into 32KB double-buffered
// LDS shared by both waves. Merge semantics identical to r17.
// ---------------------------------------------------------------------------
__global__ __launch_bounds__(128, 2) void rvq_screen_kernel(
    const float* __restrict__ xr, const f16x8* __restrict__ EfC,
    const float* __restrict__ sume, int* __restrict__ idx_ws,
    int* __restrict__ fix_list, int* __restrict__ fix_cnt,
    float* __restrict__ idxf) {
  __shared__ f16x8 ldsB[2][8][2][64];   // [buf][ni][hi/lo][lane], 32 KB

  const int tid  = threadIdx.x;        // 0..127
  const int lane = tid & 63;
  const int w    = tid >> 6;            // wave 0..1
  const int m0w  = blockIdx.x * 64 + w * 32;   // wave owns 32 tokens

  // ---- A: load + convert this wave's 32 tokens (full K) into registers ----
  f16x8 ah[2][8], al[2][8];
  #pragma unroll
  for (int mg = 0; mg < 2; ++mg) {
    const float* base =
        &xr[(size_t)(m0w + mg * 16 + (lane & 15)) * DIM + ((lane >> 4) << 3)];
    #pragma unroll
    for (int kc = 0; kc < 8; ++kc) {
      float4 u = *(const float4*)(base + kc * 32);
      float4 v = *(const float4*)(base + kc * 32 + 4);
      float xv[8] = {u.x, u.y, u.z, u.w, v.x, v.y, v.z, v.w};
      #pragma unroll
      for (int i = 0; i < 8; ++i) {
        _Float16 h = (_Float16)xv[i];
        ah[mg][kc][i] = h; al[mg][kc][i] = (_Float16)(xv[i] - (float)h);
      }
    }
  }

  float rv1[2][4], rv2[2][4]; int ri1[2][4];
  #pragma unroll
  for (int mg = 0; mg < 2; ++mg)
    #pragma unroll
    for (int r = 0; r < 4; ++r) {
      rv1[mg][r] = 3.0e38f; rv2[mg][r] = 3.0e38f; ri1[mg][r] = 0x7fffffff;
    }

  // B stage: 16KB per (ntile,kc): 1024 f16x8 entries, 8 per thread (128 thr).
#define STAGE_B(BUF, NT, KC)                                                 \
  { _Pragma("unroll")                                                        \
    for (int cc = 0; cc < 8; ++cc) {                                         \
      int e = cc * 128 + tid;                                                \
      int ln = e & 63, p = e >> 6;          /* piece 0..15 */                \
      int ni = p >> 1, half = p & 1;                                         \
      ldsB[BUF][ni][half][ln] =                                              \
          EfC[(((size_t)(NT) * 8 + ni) * 16 + (half ? (KC) + 8 : (KC))) * 64 + ln]; \
    } }

  f32x4 acc[2][8];
  #pragma unroll
  for (int mg = 0; mg < 2; ++mg)
    #pragma unroll
    for (int ni = 0; ni < 8; ++ni) acc[mg][ni] = (f32x4){0.f, 0.f, 0.f, 0.f};

  STAGE_B(0, 0, 0)
  __syncthreads();

  #pragma unroll 1
  for (int ntile = 0; ntile < 8; ++ntile) {
    #pragma unroll
    for (int kc = 0; kc < 8; ++kc) {                // static kc -> ah[.][kc] in regs
      const int buf = kc & 1;
      if (ntile * 8 + kc < 63) {
        int nt2 = (kc < 7) ? ntile : ntile + 1;
        STAGE_B(buf ^ 1, nt2, (kc + 1) & 7)
      }
      #pragma unroll
      for (int ni = 0; ni < 8; ++ni) {
        f16x8 bh = ldsB[buf][ni][0][lane];
        f16x8 bl = ldsB[buf][ni][1][lane];
        #pragma unroll
        for (int mg = 0; mg < 2; ++mg) {
          acc[mg][ni] = __builtin_amdgcn_mfma_f32_16x16x32_f16(ah[mg][kc], bh, acc[mg][ni], 0, 0, 0);
          acc[mg][ni] = __builtin_amdgcn_mfma_f32_16x16x32_f16(al[mg][kc], bh, acc[mg][ni], 0, 0, 0);
          acc[mg][ni] = __builtin_amdgcn_mfma_f32_16x16x32_f16(ah[mg][kc], bl, acc[mg][ni], 0, 0, 0);
        }
      }
      __syncthreads();
    }
    // ---- epilogue for this ntile: best/second over 128 ks, merge running ----
    const int n0 = ntile * 128;
    float se[8];
    #pragma unroll
    for (int ni = 0; ni < 8; ++ni) se[ni] = sume[n0 + ni * 16 + (lane & 15)];
    #pragma unroll
    for (int mg = 0; mg < 2; ++mg) {
      #pragma unroll
      for (int r = 0; r < 4; ++r) {
        float v1 = 3.0e38f, v2 = 3.0e38f; int i1 = 0x7fffffff;
        #pragma unroll
        for (int ni = 0; ni < 8; ++ni) {
          float key = fmaf(-2.0f, acc[mg][ni][r], se[ni]);
          int   k   = n0 + ni * 16 + (lane & 15);
          if (key < v1 || (key == v1 && k < i1)) { v2 = v1; v1 = key; i1 = k; }
          else { v2 = fminf(v2, key); }
        }
        #pragma unroll
        for (int off = 1; off < 16; off <<= 1) {
          float ov1 = __shfl_xor(v1, off, 64);
          int   oi1 = __shfl_xor(i1, off, 64);
          float ov2 = __shfl_xor(v2, off, 64);
          if (ov1 < v1 || (ov1 == v1 && oi1 < i1)) { v2 = fminf(ov2, v1); v1 = ov1; i1 = oi1; }
          else { v2 = fminf(v2, fminf(ov1, ov2)); }
        }
        if (v1 < rv1[mg][r] || (v1 == rv1[mg][r] && i1 < ri1[mg][r])) {
          rv2[mg][r] = fminf(rv1[mg][r], v2); rv1[mg][r] = v1; ri1[mg][r] = i1;
        } else { rv2[mg][r] = fminf(rv2[mg][r], fminf(v1, v2)); }
      }
      #pragma unroll
      for (int ni = 0; ni < 8; ++ni) acc[mg][ni] = (f32x4){0.f, 0.f, 0.f, 0.f};
    }
  }
#undef STAGE_B

  if ((lane & 15) == 0) {
    #pragma unroll
    for (int mg = 0; mg < 2; ++mg) {
      #pragma unroll
      for (int r = 0; r < 4; ++r) {
        int token = m0w + mg * 16 + (lane >> 4) * 4 + r;
        idx_ws[token] = ri1[mg][r];
        if (rv2[mg][r] - rv1[mg][r] < EPS_GAP) {
          int pos = atomicAdd(fix_cnt, 1);
          fix_list[pos] = token;
        }
        int b = token >> 11, n = token & (NTOK - 1);
        idxf[(size_t)b * (CBOOKS * NTOK) + n] = (float)ri1[mg][r];
      }
    }
  }
}

// Exact numpy rescan over the compacted flagged-token list (r14-verified:
// register-budgeted, unroll-1, no spill).
__global__ __launch_bounds__(256, 2) void rvq_fixup_kernel(
    const float* __restrict__ xr, const float* __restrict__ cbc,
    const float* __restrict__ sume, const int* __restrict__ fix_list,
    const int* __restrict__ fix_cnt, int* __restrict__ idx_ws,
    float* __restrict__ idxf) {
  #pragma clang fp contract(off)
  __shared__ float xs[DIM];
  __shared__ float redv[4];
  __shared__ int   redi[4];
  __shared__ float sxv_sh;
  const int tid  = threadIdx.x;
  const int nfix = *fix_cnt;

  #pragma unroll 1
  for (int i = blockIdx.x; i < nfix; i += gridDim.x) {
    int token = fix_list[i];
    __syncthreads();                           // xs reuse guard
    if (tid < 64)
      ((float4*)xs)[tid] = ((const float4*)xr)[(size_t)token * 64 + tid];
    __syncthreads();
    if (tid < 64) {
      float s = 0.f;
      if ((tid & 63) < 16) {
        int j = tid & 7, hh = (tid >> 3) & 1;
        const float* bb = xs + hh * 128;
        float r = bb[j] * bb[j];
        #pragma unroll 1
        for (int t = 1; t < 16; ++t) r = r + bb[8 * t + j] * bb[8 * t + j];
        s = r;
      }
      #pragma unroll
      for (int off = 1; off <= 8; off <<= 1)
        s = s + __shfl_xor(s, off, 64);        // commutative pairs -> exact tree
      if (tid == 0) sxv_sh = s;
    }
    __syncthreads();
    float sxv = sxv_sh;
    float bv = 3.0e38f; int bi = 0x7fffffff;
    #pragma unroll 1
    for (int kk = 0; kk < 4; ++kk) {
      int k = kk * 256 + tid;
      float4 vacc = {0.f, 0.f, 0.f, 0.f};
      #pragma unroll 1
      for (int t = 0; t < 16; ++t) {
        float4 ab = vacc;
        #pragma unroll
        for (int j = 3; j >= 0; --j) {         // reverse-chained npyv block
          float4 xq = *(const float4*)&xs[t * 16 + j * 4];
          float4 eq = *(const float4*)&cbc[(size_t)k * DIM + t * 16 + j * 4];
          ab = f4_muladd(xq, eq, ab);
        }
        vacc = ab;
      }
      float dot = (vacc.x + vacc.y) + (vacc.z + vacc.w);
      float d2  = (sxv - 2.0f * dot) + sume[k];
      if (d2 < bv || (d2 == bv && k < bi)) { bv = d2; bi = k; }
    }
    #pragma unroll
    for (int off = 1; off < 64; off <<= 1) {
      float ov = __shfl_xor(bv, off, 64);
      int   oi = __shfl_xor(bi, off, 64);
      if (ov < bv || (ov == bv && oi < bi)) { bv = ov; bi = oi; }
    }
    int w = tid >> 6;
    if ((tid & 63) == 0) { redv[w] = bv; redi[w] = bi; }
    __syncthreads();
    if (tid == 0) {
      #pragma unroll
      for (int ww = 1; ww < 4; ++ww)
        if (redv[ww] < bv || (redv[ww] == bv && redi[ww] < bi)) { bv = redv[ww]; bi = redi[ww]; }
      idx_ws[token] = bi;
      int b = token >> 11, n = token & (NTOK - 1);
      idxf[(size_t)b * (CBOOKS * NTOK) + n] = (float)bi;
    }
  }
}

// Fused update (r7-verified).
__global__ __launch_bounds__(256) void rvq_zq_resid_kernel(
    const float* __restrict__ xsrc, const float* __restrict__ cbc,
    const int* __restrict__ idx_ws, float* __restrict__ zq,
    float* __restrict__ xdst, int first, int last) {
  #pragma clang fp contract(off)
  int gid   = blockIdx.x * 256 + threadIdx.x;
  int token = gid >> 6;
  int q     = gid & 63;
  int idx   = idx_ws[token];
  float4 e = ((const float4*)cbc)[(size_t)idx * 64 + q];
  float4 x = ((const float4*)xsrc)[gid];
  float4 zi;
  zi.x = x.x + (e.x - x.x); zi.y = x.y + (e.y - x.y);
  zi.z = x.z + (e.z - x.z); zi.w = x.w + (e.w - x.w);
  float4 zo;
  if (first) { zo = zi; }
  else {
    float4 z = ((float4*)zq)[gid];
    zo.x = z.x + zi.x; zo.y = z.y + zi.y; zo.z = z.z + zi.z; zo.w = z.w + zi.w;
  }
  ((float4*)zq)[gid] = zo;
  if (!last) {
    float4 xn;
    xn.x = x.x - zo.x; xn.y = x.y - zo.y; xn.z = x.z - zo.z; xn.w = x.w - zo.w;
    ((float4*)xdst)[gid] = xn;
  }
}

// ---------------------------------------------------------------------------
extern "C" void kernel_launch(void* const* d_in, const int* in_sizes, int n_in,
                              void* d_out, int out_size, void* d_ws, size_t ws_size,
                              hipStream_t stream) {
  const float* x_in = (const float*)d_in[0];
  const float* cbs  = (const float*)d_in[1];
  float* zq      = (float*)d_out;
  float* idxbase = (float*)d_out + ZQ_ELEMS;

  // proven 40 MB footprint (r7..r17)
  char* ws = (char*)d_ws;
  float*  sume     = (float*)ws;                     // 32 KB
  int*    idx_ws   = (int*)(ws + (256 << 10));       // 128 KB
  int*    fix_list = (int*)(ws + (448 << 10));       // 128 KB
  int*    fix_cnt  = (int*)(ws + (640 << 10));       // 4 B
  f16x8*  EfC      = (f16x8*)(ws + (5 << 20));       // 1 MB
  float*  xr       = (float*)(ws + (8 << 20));       // 32 MB -> ends 40 MB

  rvq_norms_kernel<<<32, 256, 0, stream>>>(cbs, sume);
  for (int c = 0; c < CBOOKS; ++c) {
    const float* src = (c == 0) ? x_in : xr;
    const float* cbc = cbs + (size_t)c * KCB * DIM;
    float* idxf = idxbase + (size_t)c * NTOK;
    rvq_efsplit_kernel<<<16, 256, 0, stream>>>(cbc, EfC, fix_cnt);
    rvq_screen_kernel<<<512, 128, 0, stream>>>(
        src, EfC, sume + (size_t)c * KCB, idx_ws, fix_list, fix_cnt, idxf);
    rvq_fixup_kernel<<<256, 256, 0, stream>>>(
        src, cbc, sume + (size_t)c * KCB, fix_list, fix_cnt, idx_ws, idxf);
    rvq_zq_resid_kernel<<<8192, 256, 0, stream>>>(
        src, cbc, idx_ws, zq, xr, c == 0, c == CBOOKS - 1);
  }
}

// Round 19
// 2415.686 us; speedup vs baseline: 1.1479x; 1.1479x over previous
//
#include <hip/hip_runtime.h>

#define TOKENS   32768
#define DIM      256
#define KCB      1024
#define CBOOKS   8
#define NTOK     2048
#define ZQ_ELEMS (TOKENS * DIM)
#define EPS_GAP  2.0e-2f

typedef _Float16 f16x8 __attribute__((ext_vector_type(8)));
typedef float    f32x4 __attribute__((ext_vector_type(4)));

// ---------------------------------------------------------------------------
// numpy pairwise sum of squares (verified bit-exact, r6).
// ---------------------------------------------------------------------------
__device__ float np_pairwise_sumsq_256(const float4* a4) {
  #pragma clang fp contract(off)
  float h[2];
  for (int hh = 0; hh < 2; ++hh) {
    const float4* b = a4 + hh * 32;
    float4 v0 = b[0], v1 = b[1];
    float r0 = v0.x * v0.x, r1 = v0.y * v0.y, r2 = v0.z * v0.z, r3 = v0.w * v0.w;
    float r4 = v1.x * v1.x, r5 = v1.y * v1.y, r6 = v1.z * v1.z, r7 = v1.w * v1.w;
    for (int t = 1; t < 16; ++t) {
      float4 w0 = b[2 * t], w1 = b[2 * t + 1];
      r0 = r0 + w0.x * w0.x; r1 = r1 + w0.y * w0.y;
      r2 = r2 + w0.z * w0.z; r3 = r3 + w0.w * w0.w;
      r4 = r4 + w1.x * w1.x; r5 = r5 + w1.y * w1.y;
      r6 = r6 + w1.z * w1.z; r7 = r7 + w1.w * w1.w;
    }
    h[hh] = ((r0 + r1) + (r2 + r3)) + ((r4 + r5) + (r6 + r7));
  }
  return h[0] + h[1];
}

__device__ __forceinline__ float4 f4_muladd(float4 a, float4 b, float4 c) {
  #pragma clang fp contract(off)
  float4 r;
  r.x = a.x * b.x + c.x;
  r.y = a.y * b.y + c.y;
  r.z = a.z * b.z + c.z;
  r.w = a.w * b.w + c.w;
  return r;
}

__global__ __launch_bounds__(256) void rvq_norms_kernel(
    const float* __restrict__ cb, float* __restrict__ sume) {
  int row = blockIdx.x * 256 + threadIdx.x;
  sume[row] = np_pairwise_sumsq_256((const float4*)&cb[(size_t)row * DIM]);
}

// ---------------------------------------------------------------------------
// Prepack ONE codebook into fragment-linear fp16 hi/lo (r16-verified layout).
// Also zeroes the fixup counter (separate dispatch -> no race with screen).
// ---------------------------------------------------------------------------
__global__ __launch_bounds__(256) void rvq_efsplit_kernel(
    const float* __restrict__ cbc, f16x8* __restrict__ EfC,
    int* __restrict__ fix_cnt) {
  if (blockIdx.x == 0 && threadIdx.x == 0) *fix_cnt = 0;
  int gw = blockIdx.x * 4 + (threadIdx.x >> 6);   // nfrag 0..63
  int l  = threadIdx.x & 63;
  int row = gw * 16 + (l & 15);
  #pragma unroll
  for (int kb = 0; kb < 8; ++kb) {
    int d0 = kb * 32 + ((l >> 4) << 3);
    float4 u = *(const float4*)&cbc[(size_t)row * DIM + d0];
    float4 v = *(const float4*)&cbc[(size_t)row * DIM + d0 + 4];
    float ev[8] = {u.x, u.y, u.z, u.w, v.x, v.y, v.z, v.w};
    f16x8 hi, lo;
    #pragma unroll
    for (int i = 0; i < 8; ++i) {
      _Float16 h = (_Float16)ev[i];
      hi[i] = h; lo[i] = (_Float16)(ev[i] - (float)h);
    }
    EfC[((size_t)gw * 16 + kb) * 64 + l]     = hi;
    EfC[((size_t)gw * 16 + kb + 8) * 64 + l] = lo;
  }
}

// ---------------------------------------------------------------------------
// MFMA screen v4b: identical to r18's M=32/wave structure but WITHOUT the
// occupancy bound that split the unified VGPR/AGPR file and caused the
// 42 MB/dispatch spill. 512 blocks x 128 thr (2 waves); wave owns 32 tokens
// (two 16x16 A fragment sets, full K in registers -> each B LDS read feeds
// 6 MFMAs; total ds_read traffic half of r17's measured bottleneck).
// ---------------------------------------------------------------------------
__global__ __launch_bounds__(128) void rvq_screen_kernel(
    const float* __restrict__ xr, const f16x8* __restrict__ EfC,
    const float* __restrict__ sume, int* __restrict__ idx_ws,
    int* __restrict__ fix_list, int* __restrict__ fix_cnt,
    float* __restrict__ idxf) {
  __shared__ f16x8 ldsB[2][8][2][64];   // [buf][ni][hi/lo][lane], 32 KB

  const int tid  = threadIdx.x;        // 0..127
  const int lane = tid & 63;
  const int w    = tid >> 6;            // wave 0..1
  const int m0w  = blockIdx.x * 64 + w * 32;   // wave owns 32 tokens

  // ---- A: load + convert this wave's 32 tokens (full K) into registers ----
  f16x8 ah[2][8], al[2][8];
  #pragma unroll
  for (int mg = 0; mg < 2; ++mg) {
    const float* base =
        &xr[(size_t)(m0w + mg * 16 + (lane & 15)) * DIM + ((lane >> 4) << 3)];
    #pragma unroll
    for (int kc = 0; kc < 8; ++kc) {
      float4 u = *(const float4*)(base + kc * 32);
      float4 v = *(const float4*)(base + kc * 32 + 4);
      float xv[8] = {u.x, u.y, u.z, u.w, v.x, v.y, v.z, v.w};
      #pragma unroll
      for (int i = 0; i < 8; ++i) {
        _Float16 h = (_Float16)xv[i];
        ah[mg][kc][i] = h; al[mg][kc][i] = (_Float16)(xv[i] - (float)h);
      }
    }
  }

  float rv1[2][4], rv2[2][4]; int ri1[2][4];
  #pragma unroll
  for (int mg = 0; mg < 2; ++mg)
    #pragma unroll
    for (int r = 0; r < 4; ++r) {
      rv1[mg][r] = 3.0e38f; rv2[mg][r] = 3.0e38f; ri1[mg][r] = 0x7fffffff;
    }

  // B stage: 16KB per (ntile,kc): 1024 f16x8 entries, 8 per thread (128 thr).
#define STAGE_B(BUF, NT, KC)                                                 \
  { _Pragma("unroll")                                                        \
    for (int cc = 0; cc < 8; ++cc) {                                         \
      int e = cc * 128 + tid;                                                \
      int ln = e & 63, p = e >> 6;          /* piece 0..15 */                \
      int ni = p >> 1, half = p & 1;                                         \
      ldsB[BUF][ni][half][ln] =                                              \
          EfC[(((size_t)(NT) * 8 + ni) * 16 + (half ? (KC) + 8 : (KC))) * 64 + ln]; \
    } }

  f32x4 acc[2][8];
  #pragma unroll
  for (int mg = 0; mg < 2; ++mg)
    #pragma unroll
    for (int ni = 0; ni < 8; ++ni) acc[mg][ni] = (f32x4){0.f, 0.f, 0.f, 0.f};

  STAGE_B(0, 0, 0)
  __syncthreads();

  #pragma unroll 1
  for (int ntile = 0; ntile < 8; ++ntile) {
    #pragma unroll
    for (int kc = 0; kc < 8; ++kc) {                // static kc -> ah[.][kc] in regs
      const int buf = kc & 1;
      if (ntile * 8 + kc < 63) {
        int nt2 = (kc < 7) ? ntile : ntile + 1;
        STAGE_B(buf ^ 1, nt2, (kc + 1) & 7)
      }
      #pragma unroll
      for (int ni = 0; ni < 8; ++ni) {
        f16x8 bh = ldsB[buf][ni][0][lane];
        f16x8 bl = ldsB[buf][ni][1][lane];
        #pragma unroll
        for (int mg = 0; mg < 2; ++mg) {
          acc[mg][ni] = __builtin_amdgcn_mfma_f32_16x16x32_f16(ah[mg][kc], bh, acc[mg][ni], 0, 0, 0);
          acc[mg][ni] = __builtin_amdgcn_mfma_f32_16x16x32_f16(al[mg][kc], bh, acc[mg][ni], 0, 0, 0);
          acc[mg][ni] = __builtin_amdgcn_mfma_f32_16x16x32_f16(ah[mg][kc], bl, acc[mg][ni], 0, 0, 0);
        }
      }
      __syncthreads();
    }
    // ---- epilogue for this ntile: best/second over 128 ks, merge running ----
    const int n0 = ntile * 128;
    float se[8];
    #pragma unroll
    for (int ni = 0; ni < 8; ++ni) se[ni] = sume[n0 + ni * 16 + (lane & 15)];
    #pragma unroll
    for (int mg = 0; mg < 2; ++mg) {
      #pragma unroll
      for (int r = 0; r < 4; ++r) {
        float v1 = 3.0e38f, v2 = 3.0e38f; int i1 = 0x7fffffff;
        #pragma unroll
        for (int ni = 0; ni < 8; ++ni) {
          float key = fmaf(-2.0f, acc[mg][ni][r], se[ni]);
          int   k   = n0 + ni * 16 + (lane & 15);
          if (key < v1 || (key == v1 && k < i1)) { v2 = v1; v1 = key; i1 = k; }
          else { v2 = fminf(v2, key); }
        }
        #pragma unroll
        for (int off = 1; off < 16; off <<= 1) {
          float ov1 = __shfl_xor(v1, off, 64);
          int   oi1 = __shfl_xor(i1, off, 64);
          float ov2 = __shfl_xor(v2, off, 64);
          if (ov1 < v1 || (ov1 == v1 && oi1 < i1)) { v2 = fminf(ov2, v1); v1 = ov1; i1 = oi1; }
          else { v2 = fminf(v2, fminf(ov1, ov2)); }
        }
        if (v1 < rv1[mg][r] || (v1 == rv1[mg][r] && i1 < ri1[mg][r])) {
          rv2[mg][r] = fminf(rv1[mg][r], v2); rv1[mg][r] = v1; ri1[mg][r] = i1;
        } else { rv2[mg][r] = fminf(rv2[mg][r], fminf(v1, v2)); }
      }
      #pragma unroll
      for (int ni = 0; ni < 8; ++ni) acc[mg][ni] = (f32x4){0.f, 0.f, 0.f, 0.f};
    }
  }
#undef STAGE_B

  if ((lane & 15) == 0) {
    #pragma unroll
    for (int mg = 0; mg < 2; ++mg) {
      #pragma unroll
      for (int r = 0; r < 4; ++r) {
        int token = m0w + mg * 16 + (lane >> 4) * 4 + r;
        idx_ws[token] = ri1[mg][r];
        if (rv2[mg][r] - rv1[mg][r] < EPS_GAP) {
          int pos = atomicAdd(fix_cnt, 1);
          fix_list[pos] = token;
        }
        int b = token >> 11, n = token & (NTOK - 1);
        idxf[(size_t)b * (CBOOKS * NTOK) + n] = (float)ri1[mg][r];
      }
    }
  }
}

// Exact numpy rescan over the compacted flagged-token list (r14-verified:
// register-budgeted, unroll-1, no spill).
__global__ __launch_bounds__(256, 2) void rvq_fixup_kernel(
    const float* __restrict__ xr, const float* __restrict__ cbc,
    const float* __restrict__ sume, const int* __restrict__ fix_list,
    const int* __restrict__ fix_cnt, int* __restrict__ idx_ws,
    float* __restrict__ idxf) {
  #pragma clang fp contract(off)
  __shared__ float xs[DIM];
  __shared__ float redv[4];
  __shared__ int   redi[4];
  __shared__ float sxv_sh;
  const int tid  = threadIdx.x;
  const int nfix = *fix_cnt;

  #pragma unroll 1
  for (int i = blockIdx.x; i < nfix; i += gridDim.x) {
    int token = fix_list[i];
    __syncthreads();                           // xs reuse guard
    if (tid < 64)
      ((float4*)xs)[tid] = ((const float4*)xr)[(size_t)token * 64 + tid];
    __syncthreads();
    if (tid < 64) {
      float s = 0.f;
      if ((tid & 63) < 16) {
        int j = tid & 7, hh = (tid >> 3) & 1;
        const float* bb = xs + hh * 128;
        float r = bb[j] * bb[j];
        #pragma unroll 1
        for (int t = 1; t < 16; ++t) r = r + bb[8 * t + j] * bb[8 * t + j];
        s = r;
      }
      #pragma unroll
      for (int off = 1; off <= 8; off <<= 1)
        s = s + __shfl_xor(s, off, 64);        // commutative pairs -> exact tree
      if (tid == 0) sxv_sh = s;
    }
    __syncthreads();
    float sxv = sxv_sh;
    float bv = 3.0e38f; int bi = 0x7fffffff;
    #pragma unroll 1
    for (int kk = 0; kk < 4; ++kk) {
      int k = kk * 256 + tid;
      float4 vacc = {0.f, 0.f, 0.f, 0.f};
      #pragma unroll 1
      for (int t = 0; t < 16; ++t) {
        float4 ab = vacc;
        #pragma unroll
        for (int j = 3; j >= 0; --j) {         // reverse-chained npyv block
          float4 xq = *(const float4*)&xs[t * 16 + j * 4];
          float4 eq = *(const float4*)&cbc[(size_t)k * DIM + t * 16 + j * 4];
          ab = f4_muladd(xq, eq, ab);
        }
        vacc = ab;
      }
      float dot = (vacc.x + vacc.y) + (vacc.z + vacc.w);
      float d2  = (sxv - 2.0f * dot) + sume[k];
      if (d2 < bv || (d2 == bv && k < bi)) { bv = d2; bi = k; }
    }
    #pragma unroll
    for (int off = 1; off < 64; off <<= 1) {
      float ov = __shfl_xor(bv, off, 64);
      int   oi = __shfl_xor(bi, off, 64);
      if (ov < bv || (ov == bv && oi < bi)) { bv = ov; bi = oi; }
    }
    int w = tid >> 6;
    if ((tid & 63) == 0) { redv[w] = bv; redi[w] = bi; }
    __syncthreads();
    if (tid == 0) {
      #pragma unroll
      for (int ww = 1; ww < 4; ++ww)
        if (redv[ww] < bv || (redv[ww] == bv && redi[ww] < bi)) { bv = redv[ww]; bi = redi[ww]; }
      idx_ws[token] = bi;
      int b = token >> 11, n = token & (NTOK - 1);
      idxf[(size_t)b * (CBOOKS * NTOK) + n] = (float)bi;
    }
  }
}

// Fused update (r7-verified).
__global__ __launch_bounds__(256) void rvq_zq_resid_kernel(
    const float* __restrict__ xsrc, const float* __restrict__ cbc,
    const int* __restrict__ idx_ws, float* __restrict__ zq,
    float* __restrict__ xdst, int first, int last) {
  #pragma clang fp contract(off)
  int gid   = blockIdx.x * 256 + threadIdx.x;
  int token = gid >> 6;
  int q     = gid & 63;
  int idx   = idx_ws[token];
  float4 e = ((const float4*)cbc)[(size_t)idx * 64 + q];
  float4 x = ((const float4*)xsrc)[gid];
  float4 zi;
  zi.x = x.x + (e.x - x.x); zi.y = x.y + (e.y - x.y);
  zi.z = x.z + (e.z - x.z); zi.w = x.w + (e.w - x.w);
  float4 zo;
  if (first) { zo = zi; }
  else {
    float4 z = ((float4*)zq)[gid];
    zo.x = z.x + zi.x; zo.y = z.y + zi.y; zo.z = z.z + zi.z; zo.w = z.w + zi.w;
  }
  ((float4*)zq)[gid] = zo;
  if (!last) {
    float4 xn;
    xn.x = x.x - zo.x; xn.y = x.y - zo.y; xn.z = x.z - zo.z; xn.w = x.w - zo.w;
    ((float4*)xdst)[gid] = xn;
  }
}

// ---------------------------------------------------------------------------
extern "C" void kernel_launch(void* const* d_in, const int* in_sizes, int n_in,
                              void* d_out, int out_size, void* d_ws, size_t ws_size,
                              hipStream_t stream) {
  const float* x_in = (const float*)d_in[0];
  const float* cbs  = (const float*)d_in[1];
  float* zq      = (float*)d_out;
  float* idxbase = (float*)d_out + ZQ_ELEMS;

  // proven 40 MB footprint (r7..r17)
  char* ws = (char*)d_ws;
  float*  sume     = (float*)ws;                     // 32 KB
  int*    idx_ws   = (int*)(ws + (256 << 10));       // 128 KB
  int*    fix_list = (int*)(ws + (448 << 10));       // 128 KB
  int*    fix_cnt  = (int*)(ws + (640 << 10));       // 4 B
  f16x8*  EfC      = (f16x8*)(ws + (5 << 20));       // 1 MB
  float*  xr       = (float*)(ws + (8 << 20));       // 32 MB -> ends 40 MB

  rvq_norms_kernel<<<32, 256, 0, stream>>>(cbs, sume);
  for (int c = 0; c < CBOOKS; ++c) {
    const float* src = (c == 0) ? x_in : xr;
    const float* cbc = cbs + (size_t)c * KCB * DIM;
    float* idxf = idxbase + (size_t)c * NTOK;
    rvq_efsplit_kernel<<<16, 256, 0, stream>>>(cbc, EfC, fix_cnt);
    rvq_screen_kernel<<<512, 128, 0, stream>>>(
        src, EfC, sume + (size_t)c * KCB, idx_ws, fix_list, fix_cnt, idxf);
    rvq_fixup_kernel<<<256, 256, 0, stream>>>(
        src, cbc, sume + (size_t)c * KCB, fix_list, fix_cnt, idx_ws, idxf);
    rvq_zq_resid_kernel<<<8192, 256, 0, stream>>>(
        src, cbc, idx_ws, zq, xr, c == 0, c == CBOOKS - 1);
  }
}

// Round 20
// 1892.373 us; speedup vs baseline: 1.4653x; 1.2765x over previous
//
#include <hip/hip_runtime.h>

#define TOKENS   32768
#define DIM      256
#define KCB      1024
#define CBOOKS   8
#define NTOK     2048
#define ZQ_ELEMS (TOKENS * DIM)
#define EPS_GAP  0.25f

typedef _Float16 f16x8 __attribute__((ext_vector_type(8)));
typedef float    f32x4 __attribute__((ext_vector_type(4)));

// ---------------------------------------------------------------------------
// numpy pairwise sum of squares (verified bit-exact, r6).
// ---------------------------------------------------------------------------
__device__ float np_pairwise_sumsq_256(const float4* a4) {
  #pragma clang fp contract(off)
  float h[2];
  for (int hh = 0; hh < 2; ++hh) {
    const float4* b = a4 + hh * 32;
    float4 v0 = b[0], v1 = b[1];
    float r0 = v0.x * v0.x, r1 = v0.y * v0.y, r2 = v0.z * v0.z, r3 = v0.w * v0.w;
    float r4 = v1.x * v1.x, r5 = v1.y * v1.y, r6 = v1.z * v1.z, r7 = v1.w * v1.w;
    for (int t = 1; t < 16; ++t) {
      float4 w0 = b[2 * t], w1 = b[2 * t + 1];
      r0 = r0 + w0.x * w0.x; r1 = r1 + w0.y * w0.y;
      r2 = r2 + w0.z * w0.z; r3 = r3 + w0.w * w0.w;
      r4 = r4 + w1.x * w1.x; r5 = r5 + w1.y * w1.y;
      r6 = r6 + w1.z * w1.z; r7 = r7 + w1.w * w1.w;
    }
    h[hh] = ((r0 + r1) + (r2 + r3)) + ((r4 + r5) + (r6 + r7));
  }
  return h[0] + h[1];
}

__device__ __forceinline__ float4 f4_muladd(float4 a, float4 b, float4 c) {
  #pragma clang fp contract(off)
  float4 r;
  r.x = a.x * b.x + c.x;
  r.y = a.y * b.y + c.y;
  r.z = a.z * b.z + c.z;
  r.w = a.w * b.w + c.w;
  return r;
}

__global__ __launch_bounds__(256) void rvq_norms_kernel(
    const float* __restrict__ cb, float* __restrict__ sume) {
  int row = blockIdx.x * 256 + threadIdx.x;
  sume[row] = np_pairwise_sumsq_256((const float4*)&cb[(size_t)row * DIM]);
}

// ---------------------------------------------------------------------------
// Prepack ONE codebook into fragment-linear fp16 (HI ONLY — the 2-term
// screen x·eh needs no e-lo). Layout: EfC[(nfrag*8 + kb)*64 + lane].
// Also zeroes the fixup counter (separate dispatch -> no race with screen).
// ---------------------------------------------------------------------------
__global__ __launch_bounds__(256) void rvq_efsplit_kernel(
    const float* __restrict__ cbc, f16x8* __restrict__ EfC,
    int* __restrict__ fix_cnt) {
  if (blockIdx.x == 0 && threadIdx.x == 0) *fix_cnt = 0;
  int gw = blockIdx.x * 4 + (threadIdx.x >> 6);   // nfrag 0..63
  int l  = threadIdx.x & 63;
  int row = gw * 16 + (l & 15);
  #pragma unroll
  for (int kb = 0; kb < 8; ++kb) {
    int d0 = kb * 32 + ((l >> 4) << 3);
    float4 u = *(const float4*)&cbc[(size_t)row * DIM + d0];
    float4 v = *(const float4*)&cbc[(size_t)row * DIM + d0 + 4];
    float ev[8] = {u.x, u.y, u.z, u.w, v.x, v.y, v.z, v.w};
    f16x8 hi;
    #pragma unroll
    for (int i = 0; i < 8; ++i) hi[i] = (_Float16)ev[i];
    EfC[((size_t)gw * 8 + kb) * 64 + l] = hi;
  }
}

// ---------------------------------------------------------------------------
// MFMA screen v5: r17's verified structure (512 blocks x 256 thr, 4 waves,
// wave owns 16 tokens full-K in registers; B staged per (ntile,kc) into
// double-buffered LDS; ntile loop in-block, running best/second merge),
// but with the 2-TERM split: key = sume - 2*(xh.eh + xl.eh) = sume - 2*x.eh.
// Dropped x.el term bounded by ~0.15 worst-case -> EPS 0.25 certifies.
// LDS reads/step 16 -> 8, MFMAs 24 -> 16 (the r17-measured bottleneck).
// ---------------------------------------------------------------------------
__global__ __launch_bounds__(256, 2) void rvq_screen_kernel(
    const float* __restrict__ xr, const f16x8* __restrict__ EfC,
    const float* __restrict__ sume, int* __restrict__ idx_ws,
    int* __restrict__ fix_list, int* __restrict__ fix_cnt,
    float* __restrict__ idxf) {
  __shared__ f16x8 ldsB[2][8][64];      // [buf][ni][lane], 16 KB

  const int tid  = threadIdx.x;
  const int lane = tid & 63;
  const int w    = tid >> 6;            // wave 0..3
  const int m0w  = blockIdx.x * 64 + w * 16;

  // ---- A: load + convert this wave's 16 tokens (full K) into registers ----
  f16x8 ah[8], al[8];
  {
    const float* base = &xr[(size_t)(m0w + (lane & 15)) * DIM + ((lane >> 4) << 3)];
    #pragma unroll
    for (int kc = 0; kc < 8; ++kc) {
      float4 u = *(const float4*)(base + kc * 32);
      float4 v = *(const float4*)(base + kc * 32 + 4);
      float xv[8] = {u.x, u.y, u.z, u.w, v.x, v.y, v.z, v.w};
      #pragma unroll
      for (int i = 0; i < 8; ++i) {
        _Float16 h = (_Float16)xv[i];
        ah[kc][i] = h; al[kc][i] = (_Float16)(xv[i] - (float)h);
      }
    }
  }

  float rv1[4], rv2[4]; int ri1[4];
  #pragma unroll
  for (int r = 0; r < 4; ++r) { rv1[r] = 3.0e38f; rv2[r] = 3.0e38f; ri1[r] = 0x7fffffff; }

  // B stage: 8KB per (ntile,kc): 512 f16x8 entries, 2 per thread.
#define STAGE_B(BUF, NT, KC)                                                 \
  { _Pragma("unroll")                                                        \
    for (int cc = 0; cc < 2; ++cc) {                                         \
      int e = cc * 256 + tid;                                                \
      int ln = e & 63, ni = e >> 6;                                          \
      ldsB[BUF][ni][ln] =                                                    \
          EfC[(((size_t)(NT) * 8 + ni) * 8 + (KC)) * 64 + ln];               \
    } }

  f32x4 acc[8];
  #pragma unroll
  for (int ni = 0; ni < 8; ++ni) acc[ni] = (f32x4){0.f, 0.f, 0.f, 0.f};

  STAGE_B(0, 0, 0)
  __syncthreads();

  #pragma unroll 1
  for (int ntile = 0; ntile < 8; ++ntile) {
    #pragma unroll
    for (int kc = 0; kc < 8; ++kc) {                // static kc -> ah[kc] in regs
      const int buf = kc & 1;
      if (ntile * 8 + kc < 63) {
        int nt2 = (kc < 7) ? ntile : ntile + 1;
        STAGE_B(buf ^ 1, nt2, (kc + 1) & 7)
      }
      #pragma unroll
      for (int ni = 0; ni < 8; ++ni) {
        f16x8 bh = ldsB[buf][ni][lane];
        acc[ni] = __builtin_amdgcn_mfma_f32_16x16x32_f16(ah[kc], bh, acc[ni], 0, 0, 0);
        acc[ni] = __builtin_amdgcn_mfma_f32_16x16x32_f16(al[kc], bh, acc[ni], 0, 0, 0);
      }
      __syncthreads();
    }
    // ---- epilogue for this ntile: best/second over 128 ks, merge running ----
    const int n0 = ntile * 128;
    float se[8];
    #pragma unroll
    for (int ni = 0; ni < 8; ++ni) se[ni] = sume[n0 + ni * 16 + (lane & 15)];
    #pragma unroll
    for (int r = 0; r < 4; ++r) {
      float v1 = 3.0e38f, v2 = 3.0e38f; int i1 = 0x7fffffff;
      #pragma unroll
      for (int ni = 0; ni < 8; ++ni) {
        float key = fmaf(-2.0f, acc[ni][r], se[ni]);
        int   k   = n0 + ni * 16 + (lane & 15);
        if (key < v1 || (key == v1 && k < i1)) { v2 = v1; v1 = key; i1 = k; }
        else { v2 = fminf(v2, key); }
      }
      #pragma unroll
      for (int off = 1; off < 16; off <<= 1) {
        float ov1 = __shfl_xor(v1, off, 64);
        int   oi1 = __shfl_xor(i1, off, 64);
        float ov2 = __shfl_xor(v2, off, 64);
        if (ov1 < v1 || (ov1 == v1 && oi1 < i1)) { v2 = fminf(ov2, v1); v1 = ov1; i1 = oi1; }
        else { v2 = fminf(v2, fminf(ov1, ov2)); }
      }
      if (v1 < rv1[r] || (v1 == rv1[r] && i1 < ri1[r])) {
        rv2[r] = fminf(rv1[r], v2); rv1[r] = v1; ri1[r] = i1;
      } else { rv2[r] = fminf(rv2[r], fminf(v1, v2)); }
    }
    #pragma unroll
    for (int ni = 0; ni < 8; ++ni) acc[ni] = (f32x4){0.f, 0.f, 0.f, 0.f};
  }
#undef STAGE_B

  if ((lane & 15) == 0) {
    #pragma unroll
    for (int r = 0; r < 4; ++r) {
      int token = m0w + (lane >> 4) * 4 + r;
      idx_ws[token] = ri1[r];
      if (rv2[r] - rv1[r] < EPS_GAP) {
        int pos = atomicAdd(fix_cnt, 1);
        fix_list[pos] = token;
      }
      int b = token >> 11, n = token & (NTOK - 1);
      idxf[(size_t)b * (CBOOKS * NTOK) + n] = (float)ri1[r];
    }
  }
}

// Exact numpy rescan over the compacted flagged-token list (r14-verified:
// register-budgeted, unroll-1, no spill).
__global__ __launch_bounds__(256, 2) void rvq_fixup_kernel(
    const float* __restrict__ xr, const float* __restrict__ cbc,
    const float* __restrict__ sume, const int* __restrict__ fix_list,
    const int* __restrict__ fix_cnt, int* __restrict__ idx_ws,
    float* __restrict__ idxf) {
  #pragma clang fp contract(off)
  __shared__ float xs[DIM];
  __shared__ float redv[4];
  __shared__ int   redi[4];
  __shared__ float sxv_sh;
  const int tid  = threadIdx.x;
  const int nfix = *fix_cnt;

  #pragma unroll 1
  for (int i = blockIdx.x; i < nfix; i += gridDim.x) {
    int token = fix_list[i];
    __syncthreads();                           // xs reuse guard
    if (tid < 64)
      ((float4*)xs)[tid] = ((const float4*)xr)[(size_t)token * 64 + tid];
    __syncthreads();
    if (tid < 64) {
      float s = 0.f;
      if ((tid & 63) < 16) {
        int j = tid & 7, hh = (tid >> 3) & 1;
        const float* bb = xs + hh * 128;
        float r = bb[j] * bb[j];
        #pragma unroll 1
        for (int t = 1; t < 16; ++t) r = r + bb[8 * t + j] * bb[8 * t + j];
        s = r;
      }
      #pragma unroll
      for (int off = 1; off <= 8; off <<= 1)
        s = s + __shfl_xor(s, off, 64);        // commutative pairs -> exact tree
      if (tid == 0) sxv_sh = s;
    }
    __syncthreads();
    float sxv = sxv_sh;
    float bv = 3.0e38f; int bi = 0x7fffffff;
    #pragma unroll 1
    for (int kk = 0; kk < 4; ++kk) {
      int k = kk * 256 + tid;
      float4 vacc = {0.f, 0.f, 0.f, 0.f};
      #pragma unroll 1
      for (int t = 0; t < 16; ++t) {
        float4 ab = vacc;
        #pragma unroll
        for (int j = 3; j >= 0; --j) {         // reverse-chained npyv block
          float4 xq = *(const float4*)&xs[t * 16 + j * 4];
          float4 eq = *(const float4*)&cbc[(size_t)k * DIM + t * 16 + j * 4];
          ab = f4_muladd(xq, eq, ab);
        }
        vacc = ab;
      }
      float dot = (vacc.x + vacc.y) + (vacc.z + vacc.w);
      float d2  = (sxv - 2.0f * dot) + sume[k];
      if (d2 < bv || (d2 == bv && k < bi)) { bv = d2; bi = k; }
    }
    #pragma unroll
    for (int off = 1; off < 64; off <<= 1) {
      float ov = __shfl_xor(bv, off, 64);
      int   oi = __shfl_xor(bi, off, 64);
      if (ov < bv || (ov == bv && oi < bi)) { bv = ov; bi = oi; }
    }
    int w = tid >> 6;
    if ((tid & 63) == 0) { redv[w] = bv; redi[w] = bi; }
    __syncthreads();
    if (tid == 0) {
      #pragma unroll
      for (int ww = 1; ww < 4; ++ww)
        if (redv[ww] < bv || (redv[ww] == bv && redi[ww] < bi)) { bv = redv[ww]; bi = redi[ww]; }
      idx_ws[token] = bi;
      int b = token >> 11, n = token & (NTOK - 1);
      idxf[(size_t)b * (CBOOKS * NTOK) + n] = (float)bi;
    }
  }
}

// Fused update (r7-verified).
__global__ __launch_bounds__(256) void rvq_zq_resid_kernel(
    const float* __restrict__ xsrc, const float* __restrict__ cbc,
    const int* __restrict__ idx_ws, float* __restrict__ zq,
    float* __restrict__ xdst, int first, int last) {
  #pragma clang fp contract(off)
  int gid   = blockIdx.x * 256 + threadIdx.x;
  int token = gid >> 6;
  int q     = gid & 63;
  int idx   = idx_ws[token];
  float4 e = ((const float4*)cbc)[(size_t)idx * 64 + q];
  float4 x = ((const float4*)xsrc)[gid];
  float4 zi;
  zi.x = x.x + (e.x - x.x); zi.y = x.y + (e.y - x.y);
  zi.z = x.z + (e.z - x.z); zi.w = x.w + (e.w - x.w);
  float4 zo;
  if (first) { zo = zi; }
  else {
    float4 z = ((float4*)zq)[gid];
    zo.x = z.x + zi.x; zo.y = z.y + zi.y; zo.z = z.z + zi.z; zo.w = z.w + zi.w;
  }
  ((float4*)zq)[gid] = zo;
  if (!last) {
    float4 xn;
    xn.x = x.x - zo.x; xn.y = x.y - zo.y; xn.z = x.z - zo.z; xn.w = x.w - zo.w;
    ((float4*)xdst)[gid] = xn;
  }
}

// ---------------------------------------------------------------------------
extern "C" void kernel_launch(void* const* d_in, const int* in_sizes, int n_in,
                              void* d_out, int out_size, void* d_ws, size_t ws_size,
                              hipStream_t stream) {
  const float* x_in = (const float*)d_in[0];
  const float* cbs  = (const float*)d_in[1];
  float* zq      = (float*)d_out;
  float* idxbase = (float*)d_out + ZQ_ELEMS;

  // proven 40 MB footprint (r7..r17)
  char* ws = (char*)d_ws;
  float*  sume     = (float*)ws;                     // 32 KB
  int*    idx_ws   = (int*)(ws + (256 << 10));       // 128 KB
  int*    fix_list = (int*)(ws + (448 << 10));       // 128 KB
  int*    fix_cnt  = (int*)(ws + (640 << 10));       // 4 B
  f16x8*  EfC      = (f16x8*)(ws + (5 << 20));       // 512 KB (hi only)
  float*  xr       = (float*)(ws + (8 << 20));       // 32 MB -> ends 40 MB

  rvq_norms_kernel<<<32, 256, 0, stream>>>(cbs, sume);
  for (int c = 0; c < CBOOKS; ++c) {
    const float* src = (c == 0) ? x_in : xr;
    const float* cbc = cbs + (size_t)c * KCB * DIM;
    float* idxf = idxbase + (size_t)c * NTOK;
    rvq_efsplit_kernel<<<16, 256, 0, stream>>>(cbc, EfC, fix_cnt);
    rvq_screen_kernel<<<512, 256, 0, stream>>>(
        src, EfC, sume + (size_t)c * KCB, idx_ws, fix_list, fix_cnt, idxf);
    rvq_fixup_kernel<<<256, 256, 0, stream>>>(
        src, cbc, sume + (size_t)c * KCB, fix_list, fix_cnt, idx_ws, idxf);
    rvq_zq_resid_kernel<<<8192, 256, 0, stream>>>(
        src, cbc, idx_ws, zq, xr, c == 0, c == CBOOKS - 1);
  }
}

// Round 22
// 1109.892 us; speedup vs baseline: 2.4983x; 1.7050x over previous
//
#include <hip/hip_runtime.h>

#define TOKENS   32768
#define DIM      256
#define KCB      1024
#define CBOOKS   8
#define NTOK     2048
#define ZQ_ELEMS (TOKENS * DIM)
#define EPS_GAP  2.0e-2f

typedef _Float16 f16x8 __attribute__((ext_vector_type(8)));
typedef float    f32x4 __attribute__((ext_vector_type(4)));

// ---------------------------------------------------------------------------
// numpy pairwise sum of squares (verified bit-exact, r6).
// ---------------------------------------------------------------------------
__device__ float np_pairwise_sumsq_256(const float4* a4) {
  #pragma clang fp contract(off)
  float h[2];
  for (int hh = 0; hh < 2; ++hh) {
    const float4* b = a4 + hh * 32;
    float4 v0 = b[0], v1 = b[1];
    float r0 = v0.x * v0.x, r1 = v0.y * v0.y, r2 = v0.z * v0.z, r3 = v0.w * v0.w;
    float r4 = v1.x * v1.x, r5 = v1.y * v1.y, r6 = v1.z * v1.z, r7 = v1.w * v1.w;
    for (int t = 1; t < 16; ++t) {
      float4 w0 = b[2 * t], w1 = b[2 * t + 1];
      r0 = r0 + w0.x * w0.x; r1 = r1 + w0.y * w0.y;
      r2 = r2 + w0.z * w0.z; r3 = r3 + w0.w * w0.w;
      r4 = r4 + w1.x * w1.x; r5 = r5 + w1.y * w1.y;
      r6 = r6 + w1.z * w1.z; r7 = r7 + w1.w * w1.w;
    }
    h[hh] = ((r0 + r1) + (r2 + r3)) + ((r4 + r5) + (r6 + r7));
  }
  return h[0] + h[1];
}

__device__ __forceinline__ float4 f4_muladd(float4 a, float4 b, float4 c) {
  #pragma clang fp contract(off)
  float4 r;
  r.x = a.x * b.x + c.x;
  r.y = a.y * b.y + c.y;
  r.z = a.z * b.z + c.z;
  r.w = a.w * b.w + c.w;
  return r;
}

__global__ __launch_bounds__(256) void rvq_norms_kernel(
    const float* __restrict__ cb, float* __restrict__ sume) {
  int row = blockIdx.x * 256 + threadIdx.x;
  sume[row] = np_pairwise_sumsq_256((const float4*)&cb[(size_t)row * DIM]);
}

// ---------------------------------------------------------------------------
// Prepack ONE codebook into fragment-linear fp16 hi/lo (r16/r17-verified
// layout): EfC[(nfrag*16 + kb)*64 + lane], kb 0-7 = hi, 8-15 = lo.
// Also zeroes the fixup counter (separate dispatch -> no race with screen).
// ---------------------------------------------------------------------------
__global__ __launch_bounds__(256) void rvq_efsplit_kernel(
    const float* __restrict__ cbc, f16x8* __restrict__ EfC,
    int* __restrict__ fix_cnt) {
  if (blockIdx.x == 0 && threadIdx.x == 0) *fix_cnt = 0;
  int gw = blockIdx.x * 4 + (threadIdx.x >> 6);   // nfrag 0..63
  int l  = threadIdx.x & 63;
  int row = gw * 16 + (l & 15);
  #pragma unroll
  for (int kb = 0; kb < 8; ++kb) {
    int d0 = kb * 32 + ((l >> 4) << 3);
    float4 u = *(const float4*)&cbc[(size_t)row * DIM + d0];
    float4 v = *(const float4*)&cbc[(size_t)row * DIM + d0 + 4];
    float ev[8] = {u.x, u.y, u.z, u.w, v.x, v.y, v.z, v.w};
    f16x8 hi, lo;
    #pragma unroll
    for (int i = 0; i < 8; ++i) {
      _Float16 h = (_Float16)ev[i];
      hi[i] = h; lo[i] = (_Float16)(ev[i] - (float)h);
    }
    EfC[((size_t)gw * 16 + kb) * 64 + l]     = hi;
    EfC[((size_t)gw * 16 + kb + 8) * 64 + l] = lo;
  }
}

// ---------------------------------------------------------------------------
// MFMA screen v6: r17-verified values/structure (3-term key, 4 waves x 16
// tokens full-K in regs, in-block ntile loop + running best/second merge),
// with B traffic split across ports: bh staged in LDS (16 KB dbuf, half of
// r17's LDS traffic = the measured bottleneck); bl prefetched one step ahead
// REGISTER-direct from EfC (L2-resident) on the parallel vector-mem path.
// Parity-static blA/blB arrays (kc static in unrolled loop; rule #20 safe).
// MFMA operand order identical to r17 -> bit-identical keys.
// ---------------------------------------------------------------------------
__global__ __launch_bounds__(256, 2) void rvq_screen_kernel(
    const float* __restrict__ xr, const f16x8* __restrict__ EfC,
    const float* __restrict__ sume, int* __restrict__ idx_ws,
    int* __restrict__ fix_list, int* __restrict__ fix_cnt,
    float* __restrict__ idxf) {
  __shared__ f16x8 ldsB[2][8][64];      // [buf][ni][lane], hi only, 16 KB

  const int tid  = threadIdx.x;
  const int lane = tid & 63;
  const int w    = tid >> 6;            // wave 0..3
  const int m0w  = blockIdx.x * 64 + w * 16;

  // ---- A: load + convert this wave's 16 tokens (full K) into registers ----
  f16x8 ah[8], al[8];
  {
    const float* base = &xr[(size_t)(m0w + (lane & 15)) * DIM + ((lane >> 4) << 3)];
    #pragma unroll
    for (int kc = 0; kc < 8; ++kc) {
      float4 u = *(const float4*)(base + kc * 32);
      float4 v = *(const float4*)(base + kc * 32 + 4);
      float xv[8] = {u.x, u.y, u.z, u.w, v.x, v.y, v.z, v.w};
      #pragma unroll
      for (int i = 0; i < 8; ++i) {
        _Float16 h = (_Float16)xv[i];
        ah[kc][i] = h; al[kc][i] = (_Float16)(xv[i] - (float)h);
      }
    }
  }

  float rv1[4], rv2[4]; int ri1[4];
  #pragma unroll
  for (int r = 0; r < 4; ++r) { rv1[r] = 3.0e38f; rv2[r] = 3.0e38f; ri1[r] = 0x7fffffff; }

  // bh stage: 8KB per (ntile,kc): 512 f16x8 entries, 2 per thread.
#define STAGE_B(BUF, NT, KC)                                                 \
  { _Pragma("unroll")                                                        \
    for (int cc = 0; cc < 2; ++cc) {                                         \
      int e = cc * 256 + tid;                                                \
      int ln = e & 63, ni = e >> 6;                                          \
      ldsB[BUF][ni][ln] =                                                    \
          EfC[(((size_t)(NT) * 8 + ni) * 16 + (KC)) * 64 + ln];              \
    } }

  // bl prefetch: register-direct from EfC (lo slots kb = KC+8)
#define LOAD_BL(ARR, NT, KC)                                                 \
  { _Pragma("unroll")                                                        \
    for (int ni = 0; ni < 8; ++ni)                                           \
      ARR[ni] = EfC[(((size_t)(NT) * 8 + ni) * 16 + (KC) + 8) * 64 + lane]; }

#define MFMA_STEP(BUF, ARR, KC)                                              \
  { _Pragma("unroll")                                                        \
    for (int ni = 0; ni < 8; ++ni) {                                         \
      f16x8 bh = ldsB[BUF][ni][lane];                                        \
      acc[ni] = __builtin_amdgcn_mfma_f32_16x16x32_f16(ah[KC], bh, acc[ni], 0, 0, 0); \
      acc[ni] = __builtin_amdgcn_mfma_f32_16x16x32_f16(al[KC], bh, acc[ni], 0, 0, 0); \
      acc[ni] = __builtin_amdgcn_mfma_f32_16x16x32_f16(ah[KC], ARR[ni], acc[ni], 0, 0, 0); \
    } }

  f16x8 blA[8], blB[8];
  f32x4 acc[8];
  #pragma unroll
  for (int ni = 0; ni < 8; ++ni) acc[ni] = (f32x4){0.f, 0.f, 0.f, 0.f};

  LOAD_BL(blA, 0, 0)
  STAGE_B(0, 0, 0)
  __syncthreads();

  #pragma unroll 1
  for (int ntile = 0; ntile < 8; ++ntile) {
    #pragma unroll
    for (int kc = 0; kc < 8; ++kc) {                // static kc
      const int buf = kc & 1;
      if (ntile * 8 + kc < 63) {
        int nt2 = (kc < 7) ? ntile : ntile + 1;
        int kc2 = (kc + 1) & 7;
        STAGE_B(buf ^ 1, nt2, kc2)
        if ((kc & 1) == 0) { LOAD_BL(blB, nt2, kc2) }
        else               { LOAD_BL(blA, nt2, kc2) }
      }
      if ((kc & 1) == 0) { MFMA_STEP(buf, blA, kc) }
      else               { MFMA_STEP(buf, blB, kc) }
      __syncthreads();
    }
    // ---- epilogue for this ntile: best/second over 128 ks, merge running ----
    const int n0 = ntile * 128;
    float se[8];
    #pragma unroll
    for (int ni = 0; ni < 8; ++ni) se[ni] = sume[n0 + ni * 16 + (lane & 15)];
    #pragma unroll
    for (int r = 0; r < 4; ++r) {
      float v1 = 3.0e38f, v2 = 3.0e38f; int i1 = 0x7fffffff;
      #pragma unroll
      for (int ni = 0; ni < 8; ++ni) {
        float key = fmaf(-2.0f, acc[ni][r], se[ni]);
        int   k   = n0 + ni * 16 + (lane & 15);
        if (key < v1 || (key == v1 && k < i1)) { v2 = v1; v1 = key; i1 = k; }
        else { v2 = fminf(v2, key); }
      }
      #pragma unroll
      for (int off = 1; off < 16; off <<= 1) {
        float ov1 = __shfl_xor(v1, off, 64);
        int   oi1 = __shfl_xor(i1, off, 64);
        float ov2 = __shfl_xor(v2, off, 64);
        if (ov1 < v1 || (ov1 == v1 && oi1 < i1)) { v2 = fminf(ov2, v1); v1 = ov1; i1 = oi1; }
        else { v2 = fminf(v2, fminf(ov1, ov2)); }
      }
      if (v1 < rv1[r] || (v1 == rv1[r] && i1 < ri1[r])) {
        rv2[r] = fminf(rv1[r], v2); rv1[r] = v1; ri1[r] = i1;
      } else { rv2[r] = fminf(rv2[r], fminf(v1, v2)); }
    }
    #pragma unroll
    for (int ni = 0; ni < 8; ++ni) acc[ni] = (f32x4){0.f, 0.f, 0.f, 0.f};
  }
#undef STAGE_B
#undef LOAD_BL
#undef MFMA_STEP

  if ((lane & 15) == 0) {
    #pragma unroll
    for (int r = 0; r < 4; ++r) {
      int token = m0w + (lane >> 4) * 4 + r;
      idx_ws[token] = ri1[r];
      if (rv2[r] - rv1[r] < EPS_GAP) {
        int pos = atomicAdd(fix_cnt, 1);
        fix_list[pos] = token;
      }
      int b = token >> 11, n = token & (NTOK - 1);
      idxf[(size_t)b * (CBOOKS * NTOK) + n] = (float)ri1[r];
    }
  }
}

// Exact numpy rescan over the compacted flagged-token list (r14-verified:
// register-budgeted, unroll-1, no spill).
__global__ __launch_bounds__(256, 2) void rvq_fixup_kernel(
    const float* __restrict__ xr, const float* __restrict__ cbc,
    const float* __restrict__ sume, const int* __restrict__ fix_list,
    const int* __restrict__ fix_cnt, int* __restrict__ idx_ws,
    float* __restrict__ idxf) {
  #pragma clang fp contract(off)
  __shared__ float xs[DIM];
  __shared__ float redv[4];
  __shared__ int   redi[4];
  __shared__ float sxv_sh;
  const int tid  = threadIdx.x;
  const int nfix = *fix_cnt;

  #pragma unroll 1
  for (int i = blockIdx.x; i < nfix; i += gridDim.x) {
    int token = fix_list[i];
    __syncthreads();                           // xs reuse guard
    if (tid < 64)
      ((float4*)xs)[tid] = ((const float4*)xr)[(size_t)token * 64 + tid];
    __syncthreads();
    if (tid < 64) {
      float s = 0.f;
      if ((tid & 63) < 16) {
        int j = tid & 7, hh = (tid >> 3) & 1;
        const float* bb = xs + hh * 128;
        float r = bb[j] * bb[j];
        #pragma unroll 1
        for (int t = 1; t < 16; ++t) r = r + bb[8 * t + j] * bb[8 * t + j];
        s = r;
      }
      #pragma unroll
      for (int off = 1; off <= 8; off <<= 1)
        s = s + __shfl_xor(s, off, 64);        // commutative pairs -> exact tree
      if (tid == 0) sxv_sh = s;
    }
    __syncthreads();
    float sxv = sxv_sh;
    float bv = 3.0e38f; int bi = 0x7fffffff;
    #pragma unroll 1
    for (int kk = 0; kk < 4; ++kk) {
      int k = kk * 256 + tid;
      float4 vacc = {0.f, 0.f, 0.f, 0.f};
      #pragma unroll 1
      for (int t = 0; t < 16; ++t) {
        float4 ab = vacc;
        #pragma unroll
        for (int j = 3; j >= 0; --j) {         // reverse-chained npyv block
          float4 xq = *(const float4*)&xs[t * 16 + j * 4];
          float4 eq = *(const float4*)&cbc[(size_t)k * DIM + t * 16 + j * 4];
          ab = f4_muladd(xq, eq, ab);
        }
        vacc = ab;
      }
      float dot = (vacc.x + vacc.y) + (vacc.z + vacc.w);
      float d2  = (sxv - 2.0f * dot) + sume[k];
      if (d2 < bv || (d2 == bv && k < bi)) { bv = d2; bi = k; }
    }
    #pragma unroll
    for (int off = 1; off < 64; off <<= 1) {
      float ov = __shfl_xor(bv, off, 64);
      int   oi = __shfl_xor(bi, off, 64);
      if (ov < bv || (ov == bv && oi < bi)) { bv = ov; bi = oi; }
    }
    int w = tid >> 6;
    if ((tid & 63) == 0) { redv[w] = bv; redi[w] = bi; }
    __syncthreads();
    if (tid == 0) {
      #pragma unroll
      for (int ww = 1; ww < 4; ++ww)
        if (redv[ww] < bv || (redv[ww] == bv && redi[ww] < bi)) { bv = redv[ww]; bi = redi[ww]; }
      idx_ws[token] = bi;
      int b = token >> 11, n = token & (NTOK - 1);
      idxf[(size_t)b * (CBOOKS * NTOK) + n] = (float)bi;
    }
  }
}

// Fused update (r7-verified).
__global__ __launch_bounds__(256) void rvq_zq_resid_kernel(
    const float* __restrict__ xsrc, const float* __restrict__ cbc,
    const int* __restrict__ idx_ws, float* __restrict__ zq,
    float* __restrict__ xdst, int first, int last) {
  #pragma clang fp contract(off)
  int gid   = blockIdx.x * 256 + threadIdx.x;
  int token = gid >> 6;
  int q     = gid & 63;
  int idx   = idx_ws[token];
  float4 e = ((const float4*)cbc)[(size_t)idx * 64 + q];
  float4 x = ((const float4*)xsrc)[gid];
  float4 zi;
  zi.x = x.x + (e.x - x.x); zi.y = x.y + (e.y - x.y);
  zi.z = x.z + (e.z - x.z); zi.w = x.w + (e.w - x.w);
  float4 zo;
  if (first) { zo = zi; }
  else {
    float4 z = ((float4*)zq)[gid];
    zo.x = z.x + zi.x; zo.y = z.y + zi.y; zo.z = z.z + zi.z; zo.w = z.w + zi.w;
  }
  ((float4*)zq)[gid] = zo;
  if (!last) {
    float4 xn;
    xn.x = x.x - zo.x; xn.y = x.y - zo.y; xn.z = x.z - zo.z; xn.w = x.w - zo.w;
    ((float4*)xdst)[gid] = xn;
  }
}

// ---------------------------------------------------------------------------
extern "C" void kernel_launch(void* const* d_in, const int* in_sizes, int n_in,
                              void* d_out, int out_size, void* d_ws, size_t ws_size,
                              hipStream_t stream) {
  const float* x_in = (const float*)d_in[0];
  const float* cbs  = (const float*)d_in[1];
  float* zq      = (float*)d_out;
  float* idxbase = (float*)d_out + ZQ_ELEMS;

  // proven 40 MB footprint (r7..r17)
  char* ws = (char*)d_ws;
  float*  sume     = (float*)ws;                     // 32 KB
  int*    idx_ws   = (int*)(ws + (256 << 10));       // 128 KB
  int*    fix_list = (int*)(ws + (448 << 10));       // 128 KB
  int*    fix_cnt  = (int*)(ws + (640 << 10));       // 4 B
  f16x8*  EfC      = (f16x8*)(ws + (5 << 20));       // 1 MB (hi+lo)
  float*  xr       = (float*)(ws + (8 << 20));       // 32 MB -> ends 40 MB

  rvq_norms_kernel<<<32, 256, 0, stream>>>(cbs, sume);
  for (int c = 0; c < CBOOKS; ++c) {
    const float* src = (c == 0) ? x_in : xr;
    const float* cbc = cbs + (size_t)c * KCB * DIM;
    float* idxf = idxbase + (size_t)c * NTOK;
    rvq_efsplit_kernel<<<16, 256, 0, stream>>>(cbc, EfC, fix_cnt);
    rvq_screen_kernel<<<512, 256, 0, stream>>>(
        src, EfC, sume + (size_t)c * KCB, idx_ws, fix_list, fix_cnt, idxf);
    rvq_fixup_kernel<<<256, 256, 0, stream>>>(
        src, cbc, sume + (size_t)c * KCB, fix_list, fix_cnt, idx_ws, idxf);
    rvq_zq_resid_kernel<<<8192, 256, 0, stream>>>(
        src, cbc, idx_ws, zq, xr, c == 0, c == CBOOKS - 1);
  }
}

// Round 23
// 1059.935 us; speedup vs baseline: 2.6161x; 1.0471x over previous
//
#include <hip/hip_runtime.h>

#define TOKENS   32768
#define DIM      256
#define KCB      1024
#define CBOOKS   8
#define NTOK     2048
#define ZQ_ELEMS (TOKENS * DIM)
#define EPS_GAP  2.0e-2f

typedef _Float16 f16x8 __attribute__((ext_vector_type(8)));
typedef float    f32x4 __attribute__((ext_vector_type(4)));

// ---------------------------------------------------------------------------
// numpy pairwise sum of squares (verified bit-exact, r6).
// ---------------------------------------------------------------------------
__device__ float np_pairwise_sumsq_256(const float4* a4) {
  #pragma clang fp contract(off)
  float h[2];
  for (int hh = 0; hh < 2; ++hh) {
    const float4* b = a4 + hh * 32;
    float4 v0 = b[0], v1 = b[1];
    float r0 = v0.x * v0.x, r1 = v0.y * v0.y, r2 = v0.z * v0.z, r3 = v0.w * v0.w;
    float r4 = v1.x * v1.x, r5 = v1.y * v1.y, r6 = v1.z * v1.z, r7 = v1.w * v1.w;
    for (int t = 1; t < 16; ++t) {
      float4 w0 = b[2 * t], w1 = b[2 * t + 1];
      r0 = r0 + w0.x * w0.x; r1 = r1 + w0.y * w0.y;
      r2 = r2 + w0.z * w0.z; r3 = r3 + w0.w * w0.w;
      r4 = r4 + w1.x * w1.x; r5 = r5 + w1.y * w1.y;
      r6 = r6 + w1.z * w1.z; r7 = r7 + w1.w * w1.w;
    }
    h[hh] = ((r0 + r1) + (r2 + r3)) + ((r4 + r5) + (r6 + r7));
  }
  return h[0] + h[1];
}

__device__ __forceinline__ float4 f4_muladd(float4 a, float4 b, float4 c) {
  #pragma clang fp contract(off)
  float4 r;
  r.x = a.x * b.x + c.x;
  r.y = a.y * b.y + c.y;
  r.z = a.z * b.z + c.z;
  r.w = a.w * b.w + c.w;
  return r;
}

__global__ __launch_bounds__(256) void rvq_norms_kernel(
    const float* __restrict__ cb, float* __restrict__ sume) {
  int row = blockIdx.x * 256 + threadIdx.x;
  sume[row] = np_pairwise_sumsq_256((const float4*)&cb[(size_t)row * DIM]);
}

// ---------------------------------------------------------------------------
// Prepack ONE codebook into fragment-linear fp16 hi/lo (r16/r17-verified
// layout): EfC[(nfrag*16 + kb)*64 + lane], kb 0-7 = hi, 8-15 = lo.
// Also zeroes the fixup counter (separate dispatch -> no race with screen).
// ---------------------------------------------------------------------------
__global__ __launch_bounds__(256) void rvq_efsplit_kernel(
    const float* __restrict__ cbc, f16x8* __restrict__ EfC,
    int* __restrict__ fix_cnt) {
  if (blockIdx.x == 0 && threadIdx.x == 0) *fix_cnt = 0;
  int gw = blockIdx.x * 4 + (threadIdx.x >> 6);   // nfrag 0..63
  int l  = threadIdx.x & 63;
  int row = gw * 16 + (l & 15);
  #pragma unroll
  for (int kb = 0; kb < 8; ++kb) {
    int d0 = kb * 32 + ((l >> 4) << 3);
    float4 u = *(const float4*)&cbc[(size_t)row * DIM + d0];
    float4 v = *(const float4*)&cbc[(size_t)row * DIM + d0 + 4];
    float ev[8] = {u.x, u.y, u.z, u.w, v.x, v.y, v.z, v.w};
    f16x8 hi, lo;
    #pragma unroll
    for (int i = 0; i < 8; ++i) {
      _Float16 h = (_Float16)ev[i];
      hi[i] = h; lo[i] = (_Float16)(ev[i] - (float)h);
    }
    EfC[((size_t)gw * 16 + kb) * 64 + l]     = hi;
    EfC[((size_t)gw * 16 + kb + 8) * 64 + l] = lo;
  }
}

// ---------------------------------------------------------------------------
// MFMA screen v7: r17-verified value path (3-term key, hi+lo via LDS,
// identical MFMA operand order -> bit-identical keys), but the stage chunk
// is 2 kc wide (32 KB), halving the barrier count 64 -> 32. All three prior
// screens (r16/r17/r22) sat at ~97us regardless of traffic mix; the common
// factor was 64 barrier-steps, each paying the compiler's pre-barrier
// vmcnt(0) drain. Wider chunks amortize that drain 2x.
// ldsB[buf][kcw][ni][half][lane] = 64 KB; 2 blocks/CU -> 128 KB < 160.
// ---------------------------------------------------------------------------
__global__ __launch_bounds__(256, 2) void rvq_screen_kernel(
    const float* __restrict__ xr, const f16x8* __restrict__ EfC,
    const float* __restrict__ sume, int* __restrict__ idx_ws,
    int* __restrict__ fix_list, int* __restrict__ fix_cnt,
    float* __restrict__ idxf) {
  __shared__ f16x8 ldsB[2][2][8][2][64];   // 64 KB

  const int tid  = threadIdx.x;
  const int lane = tid & 63;
  const int w    = tid >> 6;            // wave 0..3
  const int m0w  = blockIdx.x * 64 + w * 16;

  // ---- A: load + convert this wave's 16 tokens (full K) into registers ----
  f16x8 ah[8], al[8];
  {
    const float* base = &xr[(size_t)(m0w + (lane & 15)) * DIM + ((lane >> 4) << 3)];
    #pragma unroll
    for (int kc = 0; kc < 8; ++kc) {
      float4 u = *(const float4*)(base + kc * 32);
      float4 v = *(const float4*)(base + kc * 32 + 4);
      float xv[8] = {u.x, u.y, u.z, u.w, v.x, v.y, v.z, v.w};
      #pragma unroll
      for (int i = 0; i < 8; ++i) {
        _Float16 h = (_Float16)xv[i];
        ah[kc][i] = h; al[kc][i] = (_Float16)(xv[i] - (float)h);
      }
    }
  }

  float rv1[4], rv2[4]; int ri1[4];
  #pragma unroll
  for (int r = 0; r < 4; ++r) { rv1[r] = 3.0e38f; rv2[r] = 3.0e38f; ri1[r] = 0x7fffffff; }

  // Stage one 2-kc chunk: 2048 f16x8 entries, 8 per thread (32 KB).
  // p = e>>6: half = p&1, ni = (p>>1)&7, kcw = p>>4.
#define STAGE_B(BUF, NT, KCB_)                                               \
  { _Pragma("unroll")                                                        \
    for (int cc = 0; cc < 8; ++cc) {                                         \
      int e = cc * 256 + tid;                                                \
      int ln = e & 63, p = e >> 6;                                           \
      int half = p & 1, ni = (p >> 1) & 7, kcw = p >> 4;                     \
      ldsB[BUF][kcw][ni][half][ln] =                                         \
          EfC[(((size_t)(NT) * 8 + ni) * 16 + (KCB_) + kcw + (half ? 8 : 0)) \
              * 64 + ln];                                                    \
    } }

#define MFMA_CHUNK(BUF, KCB_)                                                \
  { _Pragma("unroll")                                                        \
    for (int kcw = 0; kcw < 2; ++kcw) {                                      \
      _Pragma("unroll")                                                      \
      for (int ni = 0; ni < 8; ++ni) {                                       \
        f16x8 bh = ldsB[BUF][kcw][ni][0][lane];                              \
        f16x8 bl = ldsB[BUF][kcw][ni][1][lane];                              \
        acc[ni] = __builtin_amdgcn_mfma_f32_16x16x32_f16(                    \
            ah[(KCB_) + kcw], bh, acc[ni], 0, 0, 0);                         \
        acc[ni] = __builtin_amdgcn_mfma_f32_16x16x32_f16(                    \
            al[(KCB_) + kcw], bh, acc[ni], 0, 0, 0);                         \
        acc[ni] = __builtin_amdgcn_mfma_f32_16x16x32_f16(                    \
            ah[(KCB_) + kcw], bl, acc[ni], 0, 0, 0);                         \
      }                                                                      \
    } }

  f32x4 acc[8];
  #pragma unroll
  for (int ni = 0; ni < 8; ++ni) acc[ni] = (f32x4){0.f, 0.f, 0.f, 0.f};

  STAGE_B(0, 0, 0)
  __syncthreads();

  #pragma unroll 1
  for (int ntile = 0; ntile < 8; ++ntile) {
    #pragma unroll
    for (int chunk = 0; chunk < 4; ++chunk) {       // kcb = chunk*2, static
      const int buf = chunk & 1;                    // ntile*4 even -> parity static
      if (ntile * 4 + chunk < 31) {
        int nt2  = (chunk < 3) ? ntile : ntile + 1;
        int kcb2 = ((chunk + 1) & 3) * 2;
        STAGE_B(buf ^ 1, nt2, kcb2)
      }
      MFMA_CHUNK(buf, chunk * 2)
      __syncthreads();
    }
    // ---- epilogue for this ntile: best/second over 128 ks, merge running ----
    const int n0 = ntile * 128;
    float se[8];
    #pragma unroll
    for (int ni = 0; ni < 8; ++ni) se[ni] = sume[n0 + ni * 16 + (lane & 15)];
    #pragma unroll
    for (int r = 0; r < 4; ++r) {
      float v1 = 3.0e38f, v2 = 3.0e38f; int i1 = 0x7fffffff;
      #pragma unroll
      for (int ni = 0; ni < 8; ++ni) {
        float key = fmaf(-2.0f, acc[ni][r], se[ni]);
        int   k   = n0 + ni * 16 + (lane & 15);
        if (key < v1 || (key == v1 && k < i1)) { v2 = v1; v1 = key; i1 = k; }
        else { v2 = fminf(v2, key); }
      }
      #pragma unroll
      for (int off = 1; off < 16; off <<= 1) {
        float ov1 = __shfl_xor(v1, off, 64);
        int   oi1 = __shfl_xor(i1, off, 64);
        float ov2 = __shfl_xor(v2, off, 64);
        if (ov1 < v1 || (ov1 == v1 && oi1 < i1)) { v2 = fminf(ov2, v1); v1 = ov1; i1 = oi1; }
        else { v2 = fminf(v2, fminf(ov1, ov2)); }
      }
      if (v1 < rv1[r] || (v1 == rv1[r] && i1 < ri1[r])) {
        rv2[r] = fminf(rv1[r], v2); rv1[r] = v1; ri1[r] = i1;
      } else { rv2[r] = fminf(rv2[r], fminf(v1, v2)); }
    }
    #pragma unroll
    for (int ni = 0; ni < 8; ++ni) acc[ni] = (f32x4){0.f, 0.f, 0.f, 0.f};
  }
#undef STAGE_B
#undef MFMA_CHUNK

  if ((lane & 15) == 0) {
    #pragma unroll
    for (int r = 0; r < 4; ++r) {
      int token = m0w + (lane >> 4) * 4 + r;
      idx_ws[token] = ri1[r];
      if (rv2[r] - rv1[r] < EPS_GAP) {
        int pos = atomicAdd(fix_cnt, 1);
        fix_list[pos] = token;
      }
      int b = token >> 11, n = token & (NTOK - 1);
      idxf[(size_t)b * (CBOOKS * NTOK) + n] = (float)ri1[r];
    }
  }
}

// Exact numpy rescan over the compacted flagged-token list (r14-verified:
// register-budgeted, unroll-1, no spill).
__global__ __launch_bounds__(256, 2) void rvq_fixup_kernel(
    const float* __restrict__ xr, const float* __restrict__ cbc,
    const float* __restrict__ sume, const int* __restrict__ fix_list,
    const int* __restrict__ fix_cnt, int* __restrict__ idx_ws,
    float* __restrict__ idxf) {
  #pragma clang fp contract(off)
  __shared__ float xs[DIM];
  __shared__ float redv[4];
  __shared__ int   redi[4];
  __shared__ float sxv_sh;
  const int tid  = threadIdx.x;
  const int nfix = *fix_cnt;

  #pragma unroll 1
  for (int i = blockIdx.x; i < nfix; i += gridDim.x) {
    int token = fix_list[i];
    __syncthreads();                           // xs reuse guard
    if (tid < 64)
      ((float4*)xs)[tid] = ((const float4*)xr)[(size_t)token * 64 + tid];
    __syncthreads();
    if (tid < 64) {
      float s = 0.f;
      if ((tid & 63) < 16) {
        int j = tid & 7, hh = (tid >> 3) & 1;
        const float* bb = xs + hh * 128;
        float r = bb[j] * bb[j];
        #pragma unroll 1
        for (int t = 1; t < 16; ++t) r = r + bb[8 * t + j] * bb[8 * t + j];
        s = r;
      }
      #pragma unroll
      for (int off = 1; off <= 8; off <<= 1)
        s = s + __shfl_xor(s, off, 64);        // commutative pairs -> exact tree
      if (tid == 0) sxv_sh = s;
    }
    __syncthreads();
    float sxv = sxv_sh;
    float bv = 3.0e38f; int bi = 0x7fffffff;
    #pragma unroll 1
    for (int kk = 0; kk < 4; ++kk) {
      int k = kk * 256 + tid;
      float4 vacc = {0.f, 0.f, 0.f, 0.f};
      #pragma unroll 1
      for (int t = 0; t < 16; ++t) {
        float4 ab = vacc;
        #pragma unroll
        for (int j = 3; j >= 0; --j) {         // reverse-chained npyv block
          float4 xq = *(const float4*)&xs[t * 16 + j * 4];
          float4 eq = *(const float4*)&cbc[(size_t)k * DIM + t * 16 + j * 4];
          ab = f4_muladd(xq, eq, ab);
        }
        vacc = ab;
      }
      float dot = (vacc.x + vacc.y) + (vacc.z + vacc.w);
      float d2  = (sxv - 2.0f * dot) + sume[k];
      if (d2 < bv || (d2 == bv && k < bi)) { bv = d2; bi = k; }
    }
    #pragma unroll
    for (int off = 1; off < 64; off <<= 1) {
      float ov = __shfl_xor(bv, off, 64);
      int   oi = __shfl_xor(bi, off, 64);
      if (ov < bv || (ov == bv && oi < bi)) { bv = ov; bi = oi; }
    }
    int w = tid >> 6;
    if ((tid & 63) == 0) { redv[w] = bv; redi[w] = bi; }
    __syncthreads();
    if (tid == 0) {
      #pragma unroll
      for (int ww = 1; ww < 4; ++ww)
        if (redv[ww] < bv || (redv[ww] == bv && redi[ww] < bi)) { bv = redv[ww]; bi = redi[ww]; }
      idx_ws[token] = bi;
      int b = token >> 11, n = token & (NTOK - 1);
      idxf[(size_t)b * (CBOOKS * NTOK) + n] = (float)bi;
    }
  }
}

// Fused update (r7-verified).
__global__ __launch_bounds__(256) void rvq_zq_resid_kernel(
    const float* __restrict__ xsrc, const float* __restrict__ cbc,
    const int* __restrict__ idx_ws, float* __restrict__ zq,
    float* __restrict__ xdst, int first, int last) {
  #pragma clang fp contract(off)
  int gid   = blockIdx.x * 256 + threadIdx.x;
  int token = gid >> 6;
  int q     = gid & 63;
  int idx   = idx_ws[token];
  float4 e = ((const float4*)cbc)[(size_t)idx * 64 + q];
  float4 x = ((const float4*)xsrc)[gid];
  float4 zi;
  zi.x = x.x + (e.x - x.x); zi.y = x.y + (e.y - x.y);
  zi.z = x.z + (e.z - x.z); zi.w = x.w + (e.w - x.w);
  float4 zo;
  if (first) { zo = zi; }
  else {
    float4 z = ((float4*)zq)[gid];
    zo.x = z.x + zi.x; zo.y = z.y + zi.y; zo.z = z.z + zi.z; zo.w = z.w + zi.w;
  }
  ((float4*)zq)[gid] = zo;
  if (!last) {
    float4 xn;
    xn.x = x.x - zo.x; xn.y = x.y - zo.y; xn.z = x.z - zo.z; xn.w = x.w - zo.w;
    ((float4*)xdst)[gid] = xn;
  }
}

// ---------------------------------------------------------------------------
extern "C" void kernel_launch(void* const* d_in, const int* in_sizes, int n_in,
                              void* d_out, int out_size, void* d_ws, size_t ws_size,
                              hipStream_t stream) {
  const float* x_in = (const float*)d_in[0];
  const float* cbs  = (const float*)d_in[1];
  float* zq      = (float*)d_out;
  float* idxbase = (float*)d_out + ZQ_ELEMS;

  // proven 40 MB footprint (r7..r22)
  char* ws = (char*)d_ws;
  float*  sume     = (float*)ws;                     // 32 KB
  int*    idx_ws   = (int*)(ws + (256 << 10));       // 128 KB
  int*    fix_list = (int*)(ws + (448 << 10));       // 128 KB
  int*    fix_cnt  = (int*)(ws + (640 << 10));       // 4 B
  f16x8*  EfC      = (f16x8*)(ws + (5 << 20));       // 1 MB (hi+lo)
  float*  xr       = (float*)(ws + (8 << 20));       // 32 MB -> ends 40 MB

  rvq_norms_kernel<<<32, 256, 0, stream>>>(cbs, sume);
  for (int c = 0; c < CBOOKS; ++c) {
    const float* src = (c == 0) ? x_in : xr;
    const float* cbc = cbs + (size_t)c * KCB * DIM;
    float* idxf = idxbase + (size_t)c * NTOK;
    rvq_efsplit_kernel<<<16, 256, 0, stream>>>(cbc, EfC, fix_cnt);
    rvq_screen_kernel<<<512, 256, 0, stream>>>(
        src, EfC, sume + (size_t)c * KCB, idx_ws, fix_list, fix_cnt, idxf);
    rvq_fixup_kernel<<<256, 256, 0, stream>>>(
        src, cbc, sume + (size_t)c * KCB, fix_list, fix_cnt, idx_ws, idxf);
    rvq_zq_resid_kernel<<<8192, 256, 0, stream>>>(
        src, cbc, idx_ws, zq, xr, c == 0, c == CBOOKS - 1);
  }
}

// Round 24
// 1004.764 us; speedup vs baseline: 2.7597x; 1.0549x over previous
//
#include <hip/hip_runtime.h>
#include <cstdint>

#define TOKENS   32768
#define DIM      256
#define KCB      1024
#define CBOOKS   8
#define NTOK     2048
#define ZQ_ELEMS (TOKENS * DIM)
#define EPS_GAP  2.0e-2f

typedef _Float16 f16x8 __attribute__((ext_vector_type(8)));
typedef float    f32x4 __attribute__((ext_vector_type(4)));

// ---------------------------------------------------------------------------
// numpy pairwise sum of squares (verified bit-exact, r6).
// ---------------------------------------------------------------------------
__device__ float np_pairwise_sumsq_256(const float4* a4) {
  #pragma clang fp contract(off)
  float h[2];
  for (int hh = 0; hh < 2; ++hh) {
    const float4* b = a4 + hh * 32;
    float4 v0 = b[0], v1 = b[1];
    float r0 = v0.x * v0.x, r1 = v0.y * v0.y, r2 = v0.z * v0.z, r3 = v0.w * v0.w;
    float r4 = v1.x * v1.x, r5 = v1.y * v1.y, r6 = v1.z * v1.z, r7 = v1.w * v1.w;
    for (int t = 1; t < 16; ++t) {
      float4 w0 = b[2 * t], w1 = b[2 * t + 1];
      r0 = r0 + w0.x * w0.x; r1 = r1 + w0.y * w0.y;
      r2 = r2 + w0.z * w0.z; r3 = r3 + w0.w * w0.w;
      r4 = r4 + w1.x * w1.x; r5 = r5 + w1.y * w1.y;
      r6 = r6 + w1.z * w1.z; r7 = r7 + w1.w * w1.w;
    }
    h[hh] = ((r0 + r1) + (r2 + r3)) + ((r4 + r5) + (r6 + r7));
  }
  return h[0] + h[1];
}

__device__ __forceinline__ float4 f4_muladd(float4 a, float4 b, float4 c) {
  #pragma clang fp contract(off)
  float4 r;
  r.x = a.x * b.x + c.x;
  r.y = a.y * b.y + c.y;
  r.z = a.z * b.z + c.z;
  r.w = a.w * b.w + c.w;
  return r;
}

__global__ __launch_bounds__(256) void rvq_norms_kernel(
    const float* __restrict__ cb, float* __restrict__ sume) {
  int row = blockIdx.x * 256 + threadIdx.x;
  sume[row] = np_pairwise_sumsq_256((const float4*)&cb[(size_t)row * DIM]);
}

// ---------------------------------------------------------------------------
// Prepack ONE codebook into fragment-linear fp16 hi/lo (r16/r17-verified
// layout): EfC[(nfrag*16 + kb)*64 + lane], kb 0-7 = hi, 8-15 = lo.
// Also zeroes the fixup counter (separate dispatch -> no race with screen).
// ---------------------------------------------------------------------------
__global__ __launch_bounds__(256) void rvq_efsplit_kernel(
    const float* __restrict__ cbc, f16x8* __restrict__ EfC,
    int* __restrict__ fix_cnt) {
  if (blockIdx.x == 0 && threadIdx.x == 0) *fix_cnt = 0;
  int gw = blockIdx.x * 4 + (threadIdx.x >> 6);   // nfrag 0..63
  int l  = threadIdx.x & 63;
  int row = gw * 16 + (l & 15);
  #pragma unroll
  for (int kb = 0; kb < 8; ++kb) {
    int d0 = kb * 32 + ((l >> 4) << 3);
    float4 u = *(const float4*)&cbc[(size_t)row * DIM + d0];
    float4 v = *(const float4*)&cbc[(size_t)row * DIM + d0 + 4];
    float ev[8] = {u.x, u.y, u.z, u.w, v.x, v.y, v.z, v.w};
    f16x8 hi, lo;
    #pragma unroll
    for (int i = 0; i < 8; ++i) {
      _Float16 h = (_Float16)ev[i];
      hi[i] = h; lo[i] = (_Float16)(ev[i] - (float)h);
    }
    EfC[((size_t)gw * 16 + kb) * 64 + l]     = hi;
    EfC[((size_t)gw * 16 + kb + 8) * 64 + l] = lo;
  }
}

// ---------------------------------------------------------------------------
// MFMA screen v8: r23-verified value path + schedule (3-term key, 2-kc-wide
// chunks, 32 barrier-steps), with STAGE_B switched to async
// global_load_lds(16B): LDS dest = wave-uniform base + lane*16 (p = cc*4+w is
// lane-invariant), EfC source lane-contiguous -> exact hardware pattern.
// Removes the VGPR round-trip + ds_write per staged element (transport only;
// values bit-identical to r17/r23).
// ---------------------------------------------------------------------------
__global__ __launch_bounds__(256, 2) void rvq_screen_kernel(
    const float* __restrict__ xr, const f16x8* __restrict__ EfC,
    const float* __restrict__ sume, int* __restrict__ idx_ws,
    int* __restrict__ fix_list, int* __restrict__ fix_cnt,
    float* __restrict__ idxf) {
  __shared__ f16x8 ldsB[2][2][8][2][64];   // 64 KB

  const int tid  = threadIdx.x;
  const int lane = tid & 63;
  const int w    = tid >> 6;            // wave 0..3
  const int m0w  = blockIdx.x * 64 + w * 16;

  // ---- A: load + convert this wave's 16 tokens (full K) into registers ----
  f16x8 ah[8], al[8];
  {
    const float* base = &xr[(size_t)(m0w + (lane & 15)) * DIM + ((lane >> 4) << 3)];
    #pragma unroll
    for (int kc = 0; kc < 8; ++kc) {
      float4 u = *(const float4*)(base + kc * 32);
      float4 v = *(const float4*)(base + kc * 32 + 4);
      float xv[8] = {u.x, u.y, u.z, u.w, v.x, v.y, v.z, v.w};
      #pragma unroll
      for (int i = 0; i < 8; ++i) {
        _Float16 h = (_Float16)xv[i];
        ah[kc][i] = h; al[kc][i] = (_Float16)(xv[i] - (float)h);
      }
    }
  }

  float rv1[4], rv2[4]; int ri1[4];
  #pragma unroll
  for (int r = 0; r < 4; ++r) { rv1[r] = 3.0e38f; rv2[r] = 3.0e38f; ri1[r] = 0x7fffffff; }

  // Stage one 2-kc chunk (32 KB) via async global->LDS DMA. Per (cc, wave):
  // p = cc*4 + w uniform across lanes; lane's 16B lands at base + lane*16.
#define STAGE_B(BUF, NT, KCB_)                                               \
  { _Pragma("unroll")                                                        \
    for (int cc = 0; cc < 8; ++cc) {                                         \
      int p = cc * 4 + w;                                                    \
      int half = p & 1, ni = (p >> 1) & 7, kcw = p >> 4;                     \
      const f16x8* src =                                                     \
          &EfC[(((size_t)(NT) * 8 + ni) * 16 + (KCB_) + kcw + (half ? 8 : 0))\
               * 64 + lane];                                                 \
      __builtin_amdgcn_global_load_lds(                                      \
          (const __attribute__((address_space(1))) uint32_t*)src,            \
          (__attribute__((address_space(3))) uint32_t*)&ldsB[BUF][kcw][ni][half][0], \
          16, 0, 0);                                                         \
    } }

#define MFMA_CHUNK(BUF, KCB_)                                                \
  { _Pragma("unroll")                                                        \
    for (int kcw = 0; kcw < 2; ++kcw) {                                      \
      _Pragma("unroll")                                                      \
      for (int ni = 0; ni < 8; ++ni) {                                       \
        f16x8 bh = ldsB[BUF][kcw][ni][0][lane];                              \
        f16x8 bl = ldsB[BUF][kcw][ni][1][lane];                              \
        acc[ni] = __builtin_amdgcn_mfma_f32_16x16x32_f16(                    \
            ah[(KCB_) + kcw], bh, acc[ni], 0, 0, 0);                         \
        acc[ni] = __builtin_amdgcn_mfma_f32_16x16x32_f16(                    \
            al[(KCB_) + kcw], bh, acc[ni], 0, 0, 0);                         \
        acc[ni] = __builtin_amdgcn_mfma_f32_16x16x32_f16(                    \
            ah[(KCB_) + kcw], bl, acc[ni], 0, 0, 0);                         \
      }                                                                      \
    } }

  f32x4 acc[8];
  #pragma unroll
  for (int ni = 0; ni < 8; ++ni) acc[ni] = (f32x4){0.f, 0.f, 0.f, 0.f};

  STAGE_B(0, 0, 0)
  __syncthreads();

  #pragma unroll 1
  for (int ntile = 0; ntile < 8; ++ntile) {
    #pragma unroll
    for (int chunk = 0; chunk < 4; ++chunk) {       // kcb = chunk*2, static
      const int buf = chunk & 1;                    // ntile*4 even -> parity static
      if (ntile * 4 + chunk < 31) {
        int nt2  = (chunk < 3) ? ntile : ntile + 1;
        int kcb2 = ((chunk + 1) & 3) * 2;
        STAGE_B(buf ^ 1, nt2, kcb2)
      }
      MFMA_CHUNK(buf, chunk * 2)
      __syncthreads();
    }
    // ---- epilogue for this ntile: best/second over 128 ks, merge running ----
    const int n0 = ntile * 128;
    float se[8];
    #pragma unroll
    for (int ni = 0; ni < 8; ++ni) se[ni] = sume[n0 + ni * 16 + (lane & 15)];
    #pragma unroll
    for (int r = 0; r < 4; ++r) {
      float v1 = 3.0e38f, v2 = 3.0e38f; int i1 = 0x7fffffff;
      #pragma unroll
      for (int ni = 0; ni < 8; ++ni) {
        float key = fmaf(-2.0f, acc[ni][r], se[ni]);
        int   k   = n0 + ni * 16 + (lane & 15);
        if (key < v1 || (key == v1 && k < i1)) { v2 = v1; v1 = key; i1 = k; }
        else { v2 = fminf(v2, key); }
      }
      #pragma unroll
      for (int off = 1; off < 16; off <<= 1) {
        float ov1 = __shfl_xor(v1, off, 64);
        int   oi1 = __shfl_xor(i1, off, 64);
        float ov2 = __shfl_xor(v2, off, 64);
        if (ov1 < v1 || (ov1 == v1 && oi1 < i1)) { v2 = fminf(ov2, v1); v1 = ov1; i1 = oi1; }
        else { v2 = fminf(v2, fminf(ov1, ov2)); }
      }
      if (v1 < rv1[r] || (v1 == rv1[r] && i1 < ri1[r])) {
        rv2[r] = fminf(rv1[r], v2); rv1[r] = v1; ri1[r] = i1;
      } else { rv2[r] = fminf(rv2[r], fminf(v1, v2)); }
    }
    #pragma unroll
    for (int ni = 0; ni < 8; ++ni) acc[ni] = (f32x4){0.f, 0.f, 0.f, 0.f};
  }
#undef STAGE_B
#undef MFMA_CHUNK

  if ((lane & 15) == 0) {
    #pragma unroll
    for (int r = 0; r < 4; ++r) {
      int token = m0w + (lane >> 4) * 4 + r;
      idx_ws[token] = ri1[r];
      if (rv2[r] - rv1[r] < EPS_GAP) {
        int pos = atomicAdd(fix_cnt, 1);
        fix_list[pos] = token;
      }
      int b = token >> 11, n = token & (NTOK - 1);
      idxf[(size_t)b * (CBOOKS * NTOK) + n] = (float)ri1[r];
    }
  }
}

// Exact numpy rescan over the compacted flagged-token list (r14-verified:
// register-budgeted, unroll-1, no spill).
__global__ __launch_bounds__(256, 2) void rvq_fixup_kernel(
    const float* __restrict__ xr, const float* __restrict__ cbc,
    const float* __restrict__ sume, const int* __restrict__ fix_list,
    const int* __restrict__ fix_cnt, int* __restrict__ idx_ws,
    float* __restrict__ idxf) {
  #pragma clang fp contract(off)
  __shared__ float xs[DIM];
  __shared__ float redv[4];
  __shared__ int   redi[4];
  __shared__ float sxv_sh;
  const int tid  = threadIdx.x;
  const int nfix = *fix_cnt;

  #pragma unroll 1
  for (int i = blockIdx.x; i < nfix; i += gridDim.x) {
    int token = fix_list[i];
    __syncthreads();                           // xs reuse guard
    if (tid < 64)
      ((float4*)xs)[tid] = ((const float4*)xr)[(size_t)token * 64 + tid];
    __syncthreads();
    if (tid < 64) {
      float s = 0.f;
      if ((tid & 63) < 16) {
        int j = tid & 7, hh = (tid >> 3) & 1;
        const float* bb = xs + hh * 128;
        float r = bb[j] * bb[j];
        #pragma unroll 1
        for (int t = 1; t < 16; ++t) r = r + bb[8 * t + j] * bb[8 * t + j];
        s = r;
      }
      #pragma unroll
      for (int off = 1; off <= 8; off <<= 1)
        s = s + __shfl_xor(s, off, 64);        // commutative pairs -> exact tree
      if (tid == 0) sxv_sh = s;
    }
    __syncthreads();
    float sxv = sxv_sh;
    float bv = 3.0e38f; int bi = 0x7fffffff;
    #pragma unroll 1
    for (int kk = 0; kk < 4; ++kk) {
      int k = kk * 256 + tid;
      float4 vacc = {0.f, 0.f, 0.f, 0.f};
      #pragma unroll 1
      for (int t = 0; t < 16; ++t) {
        float4 ab = vacc;
        #pragma unroll
        for (int j = 3; j >= 0; --j) {         // reverse-chained npyv block
          float4 xq = *(const float4*)&xs[t * 16 + j * 4];
          float4 eq = *(const float4*)&cbc[(size_t)k * DIM + t * 16 + j * 4];
          ab = f4_muladd(xq, eq, ab);
        }
        vacc = ab;
      }
      float dot = (vacc.x + vacc.y) + (vacc.z + vacc.w);
      float d2  = (sxv - 2.0f * dot) + sume[k];
      if (d2 < bv || (d2 == bv && k < bi)) { bv = d2; bi = k; }
    }
    #pragma unroll
    for (int off = 1; off < 64; off <<= 1) {
      float ov = __shfl_xor(bv, off, 64);
      int   oi = __shfl_xor(bi, off, 64);
      if (ov < bv || (ov == bv && oi < bi)) { bv = ov; bi = oi; }
    }
    int w = tid >> 6;
    if ((tid & 63) == 0) { redv[w] = bv; redi[w] = bi; }
    __syncthreads();
    if (tid == 0) {
      #pragma unroll
      for (int ww = 1; ww < 4; ++ww)
        if (redv[ww] < bv || (redv[ww] == bv && redi[ww] < bi)) { bv = redv[ww]; bi = redi[ww]; }
      idx_ws[token] = bi;
      int b = token >> 11, n = token & (NTOK - 1);
      idxf[(size_t)b * (CBOOKS * NTOK) + n] = (float)bi;
    }
  }
}

// Fused update (r7-verified).
__global__ __launch_bounds__(256) void rvq_zq_resid_kernel(
    const float* __restrict__ xsrc, const float* __restrict__ cbc,
    const int* __restrict__ idx_ws, float* __restrict__ zq,
    float* __restrict__ xdst, int first, int last) {
  #pragma clang fp contract(off)
  int gid   = blockIdx.x * 256 + threadIdx.x;
  int token = gid >> 6;
  int q     = gid & 63;
  int idx   = idx_ws[token];
  float4 e = ((const float4*)cbc)[(size_t)idx * 64 + q];
  float4 x = ((const float4*)xsrc)[gid];
  float4 zi;
  zi.x = x.x + (e.x - x.x); zi.y = x.y + (e.y - x.y);
  zi.z = x.z + (e.z - x.z); zi.w = x.w + (e.w - x.w);
  float4 zo;
  if (first) { zo = zi; }
  else {
    float4 z = ((float4*)zq)[gid];
    zo.x = z.x + zi.x; zo.y = z.y + zi.y; zo.z = z.z + zi.z; zo.w = z.w + zi.w;
  }
  ((float4*)zq)[gid] = zo;
  if (!last) {
    float4 xn;
    xn.x = x.x - zo.x; xn.y = x.y - zo.y; xn.z = x.z - zo.z; xn.w = x.w - zo.w;
    ((float4*)xdst)[gid] = xn;
  }
}

// ---------------------------------------------------------------------------
extern "C" void kernel_launch(void* const* d_in, const int* in_sizes, int n_in,
                              void* d_out, int out_size, void* d_ws, size_t ws_size,
                              hipStream_t stream) {
  const float* x_in = (const float*)d_in[0];
  const float* cbs  = (const float*)d_in[1];
  float* zq      = (float*)d_out;
  float* idxbase = (float*)d_out + ZQ_ELEMS;

  // proven 40 MB footprint (r7..r23)
  char* ws = (char*)d_ws;
  float*  sume     = (float*)ws;                     // 32 KB
  int*    idx_ws   = (int*)(ws + (256 << 10));       // 128 KB
  int*    fix_list = (int*)(ws + (448 << 10));       // 128 KB
  int*    fix_cnt  = (int*)(ws + (640 << 10));       // 4 B
  f16x8*  EfC      = (f16x8*)(ws + (5 << 20));       // 1 MB (hi+lo)
  float*  xr       = (float*)(ws + (8 << 20));       // 32 MB -> ends 40 MB

  rvq_norms_kernel<<<32, 256, 0, stream>>>(cbs, sume);
  for (int c = 0; c < CBOOKS; ++c) {
    const float* src = (c == 0) ? x_in : xr;
    const float* cbc = cbs + (size_t)c * KCB * DIM;
    float* idxf = idxbase + (size_t)c * NTOK;
    rvq_efsplit_kernel<<<16, 256, 0, stream>>>(cbc, EfC, fix_cnt);
    rvq_screen_kernel<<<512, 256, 0, stream>>>(
        src, EfC, sume + (size_t)c * KCB, idx_ws, fix_list, fix_cnt, idxf);
    rvq_fixup_kernel<<<256, 256, 0, stream>>>(
        src, cbc, sume + (size_t)c * KCB, fix_list, fix_cnt, idx_ws, idxf);
    rvq_zq_resid_kernel<<<8192, 256, 0, stream>>>(
        src, cbc, idx_ws, zq, xr, c == 0, c == CBOOKS - 1);
  }
}

// Round 25
// 976.570 us; speedup vs baseline: 2.8394x; 1.0289x over previous
//
#include <hip/hip_runtime.h>
#include <cstdint>

#define TOKENS   32768
#define DIM      256
#define KCB      1024
#define CBOOKS   8
#define NTOK     2048
#define ZQ_ELEMS (TOKENS * DIM)
#define EPS_GAP  2.0e-2f

typedef _Float16 f16x8 __attribute__((ext_vector_type(8)));
typedef float    f32x4 __attribute__((ext_vector_type(4)));

// ---------------------------------------------------------------------------
// numpy pairwise sum of squares (verified bit-exact, r6).
// ---------------------------------------------------------------------------
__device__ float np_pairwise_sumsq_256(const float4* a4) {
  #pragma clang fp contract(off)
  float h[2];
  for (int hh = 0; hh < 2; ++hh) {
    const float4* b = a4 + hh * 32;
    float4 v0 = b[0], v1 = b[1];
    float r0 = v0.x * v0.x, r1 = v0.y * v0.y, r2 = v0.z * v0.z, r3 = v0.w * v0.w;
    float r4 = v1.x * v1.x, r5 = v1.y * v1.y, r6 = v1.z * v1.z, r7 = v1.w * v1.w;
    for (int t = 1; t < 16; ++t) {
      float4 w0 = b[2 * t], w1 = b[2 * t + 1];
      r0 = r0 + w0.x * w0.x; r1 = r1 + w0.y * w0.y;
      r2 = r2 + w0.z * w0.z; r3 = r3 + w0.w * w0.w;
      r4 = r4 + w1.x * w1.x; r5 = r5 + w1.y * w1.y;
      r6 = r6 + w1.z * w1.z; r7 = r7 + w1.w * w1.w;
    }
    h[hh] = ((r0 + r1) + (r2 + r3)) + ((r4 + r5) + (r6 + r7));
  }
  return h[0] + h[1];
}

__device__ __forceinline__ float4 f4_muladd(float4 a, float4 b, float4 c) {
  #pragma clang fp contract(off)
  float4 r;
  r.x = a.x * b.x + c.x;
  r.y = a.y * b.y + c.y;
  r.z = a.z * b.z + c.z;
  r.w = a.w * b.w + c.w;
  return r;
}

__global__ __launch_bounds__(256) void rvq_norms_kernel(
    const float* __restrict__ cb, float* __restrict__ sume) {
  int row = blockIdx.x * 256 + threadIdx.x;
  sume[row] = np_pairwise_sumsq_256((const float4*)&cb[(size_t)row * DIM]);
}

// ---------------------------------------------------------------------------
// Prepack ONE codebook into fragment-linear fp16 hi/lo (r16/r17-verified
// layout). Also zeroes the fixup counter.
// ---------------------------------------------------------------------------
__global__ __launch_bounds__(256) void rvq_efsplit_kernel(
    const float* __restrict__ cbc, f16x8* __restrict__ EfC,
    int* __restrict__ fix_cnt) {
  if (blockIdx.x == 0 && threadIdx.x == 0) *fix_cnt = 0;
  int gw = blockIdx.x * 4 + (threadIdx.x >> 6);   // nfrag 0..63
  int l  = threadIdx.x & 63;
  int row = gw * 16 + (l & 15);
  #pragma unroll
  for (int kb = 0; kb < 8; ++kb) {
    int d0 = kb * 32 + ((l >> 4) << 3);
    float4 u = *(const float4*)&cbc[(size_t)row * DIM + d0];
    float4 v = *(const float4*)&cbc[(size_t)row * DIM + d0 + 4];
    float ev[8] = {u.x, u.y, u.z, u.w, v.x, v.y, v.z, v.w};
    f16x8 hi, lo;
    #pragma unroll
    for (int i = 0; i < 8; ++i) {
      _Float16 h = (_Float16)ev[i];
      hi[i] = h; lo[i] = (_Float16)(ev[i] - (float)h);
    }
    EfC[((size_t)gw * 16 + kb) * 64 + l]     = hi;
    EfC[((size_t)gw * 16 + kb + 8) * 64 + l] = lo;
  }
}

// ---------------------------------------------------------------------------
// MFMA screen v9 = r24-verified screen + FUSED residual update prologue.
// For pass c>=1, the prologue applies pass c-1's update inline (exact
// zq_resid fp order, contract off): zi = x+(e-x); zq_c = zq_{c-1}+zi (or zi
// at mode 1); r_c = x - zq_c. Writes zq & xr (one lane owns each element),
// and feeds r_c straight into the A hi/lo conversion -> the separate
// zq_resid dispatch and its xr re-read are eliminated for passes 0..6.
// mode: 0 = c==0 (no update), 1 = c==1 (zq_old = 0), 2 = c>=2.
// Screen values bit-identical to r24 (same keys, same EPS certification).
// ---------------------------------------------------------------------------
__global__ __launch_bounds__(256, 2) void rvq_screen_kernel(
    const float* __restrict__ xsrc, const float* __restrict__ cbp,
    const f16x8* __restrict__ EfC, const float* __restrict__ sume,
    int* __restrict__ idx_ws, int* __restrict__ fix_list,
    int* __restrict__ fix_cnt, float* __restrict__ idxf,
    float* __restrict__ zq, float* __restrict__ xr_out, int mode) {
  __shared__ f16x8 ldsB[2][2][8][2][64];   // 64 KB

  const int tid  = threadIdx.x;
  const int lane = tid & 63;
  const int w    = tid >> 6;            // wave 0..3
  const int m0w  = blockIdx.x * 64 + w * 16;

  // ---- prologue: (optional) fused update, then A hi/lo conversion ----
  f16x8 ah[8], al[8];
  {
    #pragma clang fp contract(off)
    const int tok   = m0w + (lane & 15);
    const int dbase = (lane >> 4) << 3;          // 0,8,16,24
    const float4* xp = (const float4*)(xsrc + (size_t)tok * DIM + dbase);
    const float4* ep = (const float4*)(cbp + (size_t)(mode ? idx_ws[tok] : 0) * DIM + dbase);
    const float4* zr = (const float4*)(zq + (size_t)tok * DIM + dbase);
    float4* zw = (float4*)(zq + (size_t)tok * DIM + dbase);
    float4* xw = (float4*)(xr_out + (size_t)tok * DIM + dbase);
    #pragma unroll
    for (int kc = 0; kc < 8; ++kc) {
      float4 u = xp[kc * 8], v = xp[kc * 8 + 1];
      if (mode) {
        float4 e0 = ep[kc * 8], e1 = ep[kc * 8 + 1];
        float4 zi0, zi1;
        zi0.x = u.x + (e0.x - u.x); zi0.y = u.y + (e0.y - u.y);
        zi0.z = u.z + (e0.z - u.z); zi0.w = u.w + (e0.w - u.w);
        zi1.x = v.x + (e1.x - v.x); zi1.y = v.y + (e1.y - v.y);
        zi1.z = v.z + (e1.z - v.z); zi1.w = v.w + (e1.w - v.w);
        float4 zn0, zn1;
        if (mode == 2) {
          float4 z0 = zr[kc * 8], z1 = zr[kc * 8 + 1];
          zn0.x = z0.x + zi0.x; zn0.y = z0.y + zi0.y;
          zn0.z = z0.z + zi0.z; zn0.w = z0.w + zi0.w;
          zn1.x = z1.x + zi1.x; zn1.y = z1.y + zi1.y;
          zn1.z = z1.z + zi1.z; zn1.w = z1.w + zi1.w;
        } else { zn0 = zi0; zn1 = zi1; }
        zw[kc * 8]     = zn0;
        zw[kc * 8 + 1] = zn1;
        float4 n0, n1;
        n0.x = u.x - zn0.x; n0.y = u.y - zn0.y;
        n0.z = u.z - zn0.z; n0.w = u.w - zn0.w;
        n1.x = v.x - zn1.x; n1.y = v.y - zn1.y;
        n1.z = v.z - zn1.z; n1.w = v.w - zn1.w;
        xw[kc * 8]     = n0;
        xw[kc * 8 + 1] = n1;
        u = n0; v = n1;
      }
      float xv[8] = {u.x, u.y, u.z, u.w, v.x, v.y, v.z, v.w};
      #pragma unroll
      for (int i = 0; i < 8; ++i) {
        _Float16 h = (_Float16)xv[i];
        ah[kc][i] = h; al[kc][i] = (_Float16)(xv[i] - (float)h);
      }
    }
  }

  float rv1[4], rv2[4]; int ri1[4];
  #pragma unroll
  for (int r = 0; r < 4; ++r) { rv1[r] = 3.0e38f; rv2[r] = 3.0e38f; ri1[r] = 0x7fffffff; }

  // Stage one 2-kc chunk (32 KB) via async global->LDS DMA (r24-verified).
#define STAGE_B(BUF, NT, KCB_)                                               \
  { _Pragma("unroll")                                                        \
    for (int cc = 0; cc < 8; ++cc) {                                         \
      int p = cc * 4 + w;                                                    \
      int half = p & 1, ni = (p >> 1) & 7, kcw = p >> 4;                     \
      const f16x8* src =                                                     \
          &EfC[(((size_t)(NT) * 8 + ni) * 16 + (KCB_) + kcw + (half ? 8 : 0))\
               * 64 + lane];                                                 \
      __builtin_amdgcn_global_load_lds(                                      \
          (const __attribute__((address_space(1))) uint32_t*)src,            \
          (__attribute__((address_space(3))) uint32_t*)&ldsB[BUF][kcw][ni][half][0], \
          16, 0, 0);                                                         \
    } }

#define MFMA_CHUNK(BUF, KCB_)                                                \
  { _Pragma("unroll")                                                        \
    for (int kcw = 0; kcw < 2; ++kcw) {                                      \
      _Pragma("unroll")                                                      \
      for (int ni = 0; ni < 8; ++ni) {                                       \
        f16x8 bh = ldsB[BUF][kcw][ni][0][lane];                              \
        f16x8 bl = ldsB[BUF][kcw][ni][1][lane];                              \
        acc[ni] = __builtin_amdgcn_mfma_f32_16x16x32_f16(                    \
            ah[(KCB_) + kcw], bh, acc[ni], 0, 0, 0);                         \
        acc[ni] = __builtin_amdgcn_mfma_f32_16x16x32_f16(                    \
            al[(KCB_) + kcw], bh, acc[ni], 0, 0, 0);                         \
        acc[ni] = __builtin_amdgcn_mfma_f32_16x16x32_f16(                    \
            ah[(KCB_) + kcw], bl, acc[ni], 0, 0, 0);                         \
      }                                                                      \
    } }

  f32x4 acc[8];
  #pragma unroll
  for (int ni = 0; ni < 8; ++ni) acc[ni] = (f32x4){0.f, 0.f, 0.f, 0.f};

  STAGE_B(0, 0, 0)
  __syncthreads();

  #pragma unroll 1
  for (int ntile = 0; ntile < 8; ++ntile) {
    #pragma unroll
    for (int chunk = 0; chunk < 4; ++chunk) {       // kcb = chunk*2, static
      const int buf = chunk & 1;                    // ntile*4 even -> parity static
      if (ntile * 4 + chunk < 31) {
        int nt2  = (chunk < 3) ? ntile : ntile + 1;
        int kcb2 = ((chunk + 1) & 3) * 2;
        STAGE_B(buf ^ 1, nt2, kcb2)
      }
      MFMA_CHUNK(buf, chunk * 2)
      __syncthreads();
    }
    // ---- epilogue for this ntile: best/second over 128 ks, merge running ----
    const int n0 = ntile * 128;
    float se[8];
    #pragma unroll
    for (int ni = 0; ni < 8; ++ni) se[ni] = sume[n0 + ni * 16 + (lane & 15)];
    #pragma unroll
    for (int r = 0; r < 4; ++r) {
      float v1 = 3.0e38f, v2 = 3.0e38f; int i1 = 0x7fffffff;
      #pragma unroll
      for (int ni = 0; ni < 8; ++ni) {
        float key = fmaf(-2.0f, acc[ni][r], se[ni]);
        int   k   = n0 + ni * 16 + (lane & 15);
        if (key < v1 || (key == v1 && k < i1)) { v2 = v1; v1 = key; i1 = k; }
        else { v2 = fminf(v2, key); }
      }
      #pragma unroll
      for (int off = 1; off < 16; off <<= 1) {
        float ov1 = __shfl_xor(v1, off, 64);
        int   oi1 = __shfl_xor(i1, off, 64);
        float ov2 = __shfl_xor(v2, off, 64);
        if (ov1 < v1 || (ov1 == v1 && oi1 < i1)) { v2 = fminf(ov2, v1); v1 = ov1; i1 = oi1; }
        else { v2 = fminf(v2, fminf(ov1, ov2)); }
      }
      if (v1 < rv1[r] || (v1 == rv1[r] && i1 < ri1[r])) {
        rv2[r] = fminf(rv1[r], v2); rv1[r] = v1; ri1[r] = i1;
      } else { rv2[r] = fminf(rv2[r], fminf(v1, v2)); }
    }
    #pragma unroll
    for (int ni = 0; ni < 8; ++ni) acc[ni] = (f32x4){0.f, 0.f, 0.f, 0.f};
  }
#undef STAGE_B
#undef MFMA_CHUNK

  if ((lane & 15) == 0) {
    #pragma unroll
    for (int r = 0; r < 4; ++r) {
      int token = m0w + (lane >> 4) * 4 + r;
      idx_ws[token] = ri1[r];
      if (rv2[r] - rv1[r] < EPS_GAP) {
        int pos = atomicAdd(fix_cnt, 1);
        fix_list[pos] = token;
      }
      int b = token >> 11, n = token & (NTOK - 1);
      idxf[(size_t)b * (CBOOKS * NTOK) + n] = (float)ri1[r];
    }
  }
}

// Exact numpy rescan over the compacted flagged-token list (r14-verified).
__global__ __launch_bounds__(256, 2) void rvq_fixup_kernel(
    const float* __restrict__ xr, const float* __restrict__ cbc,
    const float* __restrict__ sume, const int* __restrict__ fix_list,
    const int* __restrict__ fix_cnt, int* __restrict__ idx_ws,
    float* __restrict__ idxf) {
  #pragma clang fp contract(off)
  __shared__ float xs[DIM];
  __shared__ float redv[4];
  __shared__ int   redi[4];
  __shared__ float sxv_sh;
  const int tid  = threadIdx.x;
  const int nfix = *fix_cnt;

  #pragma unroll 1
  for (int i = blockIdx.x; i < nfix; i += gridDim.x) {
    int token = fix_list[i];
    __syncthreads();                           // xs reuse guard
    if (tid < 64)
      ((float4*)xs)[tid] = ((const float4*)xr)[(size_t)token * 64 + tid];
    __syncthreads();
    if (tid < 64) {
      float s = 0.f;
      if ((tid & 63) < 16) {
        int j = tid & 7, hh = (tid >> 3) & 1;
        const float* bb = xs + hh * 128;
        float r = bb[j] * bb[j];
        #pragma unroll 1
        for (int t = 1; t < 16; ++t) r = r + bb[8 * t + j] * bb[8 * t + j];
        s = r;
      }
      #pragma unroll
      for (int off = 1; off <= 8; off <<= 1)
        s = s + __shfl_xor(s, off, 64);        // commutative pairs -> exact tree
      if (tid == 0) sxv_sh = s;
    }
    __syncthreads();
    float sxv = sxv_sh;
    float bv = 3.0e38f; int bi = 0x7fffffff;
    #pragma unroll 1
    for (int kk = 0; kk < 4; ++kk) {
      int k = kk * 256 + tid;
      float4 vacc = {0.f, 0.f, 0.f, 0.f};
      #pragma unroll 1
      for (int t = 0; t < 16; ++t) {
        float4 ab = vacc;
        #pragma unroll
        for (int j = 3; j >= 0; --j) {         // reverse-chained npyv block
          float4 xq = *(const float4*)&xs[t * 16 + j * 4];
          float4 eq = *(const float4*)&cbc[(size_t)k * DIM + t * 16 + j * 4];
          ab = f4_muladd(xq, eq, ab);
        }
        vacc = ab;
      }
      float dot = (vacc.x + vacc.y) + (vacc.z + vacc.w);
      float d2  = (sxv - 2.0f * dot) + sume[k];
      if (d2 < bv || (d2 == bv && k < bi)) { bv = d2; bi = k; }
    }
    #pragma unroll
    for (int off = 1; off < 64; off <<= 1) {
      float ov = __shfl_xor(bv, off, 64);
      int   oi = __shfl_xor(bi, off, 64);
      if (ov < bv || (ov == bv && oi < bi)) { bv = ov; bi = oi; }
    }
    int w = tid >> 6;
    if ((tid & 63) == 0) { redv[w] = bv; redi[w] = bi; }
    __syncthreads();
    if (tid == 0) {
      #pragma unroll
      for (int ww = 1; ww < 4; ++ww)
        if (redv[ww] < bv || (redv[ww] == bv && redi[ww] < bi)) { bv = redv[ww]; bi = redi[ww]; }
      idx_ws[token] = bi;
      int b = token >> 11, n = token & (NTOK - 1);
      idxf[(size_t)b * (CBOOKS * NTOK) + n] = (float)bi;
    }
  }
}

// Final-pass update only (r7-verified fp order): zq_out = zq + zi.
__global__ __launch_bounds__(256) void rvq_zq_final_kernel(
    const float* __restrict__ xsrc, const float* __restrict__ cbc,
    const int* __restrict__ idx_ws, float* __restrict__ zq) {
  #pragma clang fp contract(off)
  int gid   = blockIdx.x * 256 + threadIdx.x;
  int token = gid >> 6;
  int q     = gid & 63;
  int idx   = idx_ws[token];
  float4 e = ((const float4*)cbc)[(size_t)idx * 64 + q];
  float4 x = ((const float4*)xsrc)[gid];
  float4 zi;
  zi.x = x.x + (e.x - x.x); zi.y = x.y + (e.y - x.y);
  zi.z = x.z + (e.z - x.z); zi.w = x.w + (e.w - x.w);
  float4 z = ((float4*)zq)[gid];
  float4 zo;
  zo.x = z.x + zi.x; zo.y = z.y + zi.y; zo.z = z.z + zi.z; zo.w = z.w + zi.w;
  ((float4*)zq)[gid] = zo;
}

// ---------------------------------------------------------------------------
extern "C" void kernel_launch(void* const* d_in, const int* in_sizes, int n_in,
                              void* d_out, int out_size, void* d_ws, size_t ws_size,
                              hipStream_t stream) {
  const float* x_in = (const float*)d_in[0];
  const float* cbs  = (const float*)d_in[1];
  float* zq      = (float*)d_out;
  float* idxbase = (float*)d_out + ZQ_ELEMS;

  // proven 40 MB footprint (r7..r24)
  char* ws = (char*)d_ws;
  float*  sume     = (float*)ws;                     // 32 KB
  int*    idx_ws   = (int*)(ws + (256 << 10));       // 128 KB
  int*    fix_list = (int*)(ws + (448 << 10));       // 128 KB
  int*    fix_cnt  = (int*)(ws + (640 << 10));       // 4 B
  f16x8*  EfC      = (f16x8*)(ws + (5 << 20));       // 1 MB (hi+lo)
  float*  xr       = (float*)(ws + (8 << 20));       // 32 MB -> ends 40 MB

  rvq_norms_kernel<<<32, 256, 0, stream>>>(cbs, sume);
  for (int c = 0; c < CBOOKS; ++c) {
    // screen(c) prologue applies pass c-1's update:
    //   xsrc = r_{c-1}: x_in for c<=1, else xr;  e-gather from codebook c-1.
    const float* xsrc = (c <= 1) ? x_in : xr;
    const float* cbp  = cbs + (size_t)(c > 0 ? c - 1 : 0) * KCB * DIM;
    const float* cbc  = cbs + (size_t)c * KCB * DIM;
    float* idxf = idxbase + (size_t)c * NTOK;
    int mode = (c == 0) ? 0 : (c == 1) ? 1 : 2;
    rvq_efsplit_kernel<<<16, 256, 0, stream>>>(cbc, EfC, fix_cnt);
    rvq_screen_kernel<<<512, 256, 0, stream>>>(
        xsrc, cbp, EfC, sume + (size_t)c * KCB, idx_ws, fix_list, fix_cnt,
        idxf, zq, xr, mode);
    rvq_fixup_kernel<<<256, 256, 0, stream>>>(
        (c == 0) ? x_in : xr, cbc, sume + (size_t)c * KCB,
        fix_list, fix_cnt, idx_ws, idxf);
  }
  // final pass-7 update: zq += zi_7 (reads r_7 = xr, idx_7)
  rvq_zq_final_kernel<<<8192, 256, 0, stream>>>(
      xr, cbs + (size_t)(CBOOKS - 1) * KCB * DIM, idx_ws, zq);
}

// Round 26
// 960.778 us; speedup vs baseline: 2.8861x; 1.0164x over previous
//
#include <hip/hip_runtime.h>
#include <cstdint>

#define TOKENS   32768
#define DIM      256
#define KCB      1024
#define CBOOKS   8
#define NTOK     2048
#define ZQ_ELEMS (TOKENS * DIM)
#define EPS_GAP  2.0e-2f

typedef _Float16 f16x8 __attribute__((ext_vector_type(8)));
typedef float    f32x4 __attribute__((ext_vector_type(4)));

// ---------------------------------------------------------------------------
// numpy pairwise sum of squares (verified bit-exact, r6).
// ---------------------------------------------------------------------------
__device__ float np_pairwise_sumsq_256(const float4* a4) {
  #pragma clang fp contract(off)
  float h[2];
  for (int hh = 0; hh < 2; ++hh) {
    const float4* b = a4 + hh * 32;
    float4 v0 = b[0], v1 = b[1];
    float r0 = v0.x * v0.x, r1 = v0.y * v0.y, r2 = v0.z * v0.z, r3 = v0.w * v0.w;
    float r4 = v1.x * v1.x, r5 = v1.y * v1.y, r6 = v1.z * v1.z, r7 = v1.w * v1.w;
    for (int t = 1; t < 16; ++t) {
      float4 w0 = b[2 * t], w1 = b[2 * t + 1];
      r0 = r0 + w0.x * w0.x; r1 = r1 + w0.y * w0.y;
      r2 = r2 + w0.z * w0.z; r3 = r3 + w0.w * w0.w;
      r4 = r4 + w1.x * w1.x; r5 = r5 + w1.y * w1.y;
      r6 = r6 + w1.z * w1.z; r7 = r7 + w1.w * w1.w;
    }
    h[hh] = ((r0 + r1) + (r2 + r3)) + ((r4 + r5) + (r6 + r7));
  }
  return h[0] + h[1];
}

__device__ __forceinline__ float4 f4_muladd(float4 a, float4 b, float4 c) {
  #pragma clang fp contract(off)
  float4 r;
  r.x = a.x * b.x + c.x;
  r.y = a.y * b.y + c.y;
  r.z = a.z * b.z + c.z;
  r.w = a.w * b.w + c.w;
  return r;
}

// Prepack helper: fragment-linear fp16 hi/lo for one codebook (r16-verified
// layout). gw = nfrag 0..63, l = lane.
__device__ __forceinline__ void prepack_cb(
    const float* __restrict__ cbc, f16x8* __restrict__ EfC, int gw, int l) {
  int row = gw * 16 + (l & 15);
  #pragma unroll
  for (int kb = 0; kb < 8; ++kb) {
    int d0 = kb * 32 + ((l >> 4) << 3);
    float4 u = *(const float4*)&cbc[(size_t)row * DIM + d0];
    float4 v = *(const float4*)&cbc[(size_t)row * DIM + d0 + 4];
    float ev[8] = {u.x, u.y, u.z, u.w, v.x, v.y, v.z, v.w};
    f16x8 hi, lo;
    #pragma unroll
    for (int i = 0; i < 8; ++i) {
      _Float16 h = (_Float16)ev[i];
      hi[i] = h; lo[i] = (_Float16)(ev[i] - (float)h);
    }
    EfC[((size_t)gw * 16 + kb) * 64 + l]     = hi;
    EfC[((size_t)gw * 16 + kb + 8) * 64 + l] = lo;
  }
}

// ---------------------------------------------------------------------------
// norms (all 8192 rows) + prepack codebook 0 + zero both fix counters.
// ---------------------------------------------------------------------------
__global__ __launch_bounds__(256) void rvq_norms_kernel(
    const float* __restrict__ cbs, float* __restrict__ sume,
    f16x8* __restrict__ EfC, int* __restrict__ fix_cnt2) {
  int row = blockIdx.x * 256 + threadIdx.x;
  sume[row] = np_pairwise_sumsq_256((const float4*)&cbs[(size_t)row * DIM]);
  if (blockIdx.x == 0 && threadIdx.x < 2) fix_cnt2[threadIdx.x] = 0;
  if (blockIdx.x < 16) {
    prepack_cb(cbs, EfC, blockIdx.x * 4 + (threadIdx.x >> 6), threadIdx.x & 63);
  }
}

// ---------------------------------------------------------------------------
// MFMA screen v9 (r25-verified): fused residual-update prologue + 3-term
// hi/lo MFMA screen, 2-kc chunks, async global_load_lds B staging, in-block
// ntile loop with running best/second merge. Values bit-identical to r17+.
// mode: 0 = c==0 (no update), 1 = c==1 (zq_old = 0), 2 = c>=2.
// ---------------------------------------------------------------------------
__global__ __launch_bounds__(256, 2) void rvq_screen_kernel(
    const float* __restrict__ xsrc, const float* __restrict__ cbp,
    const f16x8* __restrict__ EfC, const float* __restrict__ sume,
    int* __restrict__ idx_ws, int* __restrict__ fix_list,
    int* __restrict__ fix_cnt, float* __restrict__ idxf,
    float* __restrict__ zq, float* __restrict__ xr_out, int mode) {
  __shared__ f16x8 ldsB[2][2][8][2][64];   // 64 KB

  const int tid  = threadIdx.x;
  const int lane = tid & 63;
  const int w    = tid >> 6;            // wave 0..3
  const int m0w  = blockIdx.x * 64 + w * 16;

  // ---- prologue: (optional) fused update, then A hi/lo conversion ----
  f16x8 ah[8], al[8];
  {
    #pragma clang fp contract(off)
    const int tok   = m0w + (lane & 15);
    const int dbase = (lane >> 4) << 3;          // 0,8,16,24
    const float4* xp = (const float4*)(xsrc + (size_t)tok * DIM + dbase);
    const float4* ep = (const float4*)(cbp + (size_t)(mode ? idx_ws[tok] : 0) * DIM + dbase);
    const float4* zr = (const float4*)(zq + (size_t)tok * DIM + dbase);
    float4* zw = (float4*)(zq + (size_t)tok * DIM + dbase);
    float4* xw = (float4*)(xr_out + (size_t)tok * DIM + dbase);
    #pragma unroll
    for (int kc = 0; kc < 8; ++kc) {
      float4 u = xp[kc * 8], v = xp[kc * 8 + 1];
      if (mode) {
        float4 e0 = ep[kc * 8], e1 = ep[kc * 8 + 1];
        float4 zi0, zi1;
        zi0.x = u.x + (e0.x - u.x); zi0.y = u.y + (e0.y - u.y);
        zi0.z = u.z + (e0.z - u.z); zi0.w = u.w + (e0.w - u.w);
        zi1.x = v.x + (e1.x - v.x); zi1.y = v.y + (e1.y - v.y);
        zi1.z = v.z + (e1.z - v.z); zi1.w = v.w + (e1.w - v.w);
        float4 zn0, zn1;
        if (mode == 2) {
          float4 z0 = zr[kc * 8], z1 = zr[kc * 8 + 1];
          zn0.x = z0.x + zi0.x; zn0.y = z0.y + zi0.y;
          zn0.z = z0.z + zi0.z; zn0.w = z0.w + zi0.w;
          zn1.x = z1.x + zi1.x; zn1.y = z1.y + zi1.y;
          zn1.z = z1.z + zi1.z; zn1.w = z1.w + zi1.w;
        } else { zn0 = zi0; zn1 = zi1; }
        zw[kc * 8]     = zn0;
        zw[kc * 8 + 1] = zn1;
        float4 n0, n1;
        n0.x = u.x - zn0.x; n0.y = u.y - zn0.y;
        n0.z = u.z - zn0.z; n0.w = u.w - zn0.w;
        n1.x = v.x - zn1.x; n1.y = v.y - zn1.y;
        n1.z = v.z - zn1.z; n1.w = v.w - zn1.w;
        xw[kc * 8]     = n0;
        xw[kc * 8 + 1] = n1;
        u = n0; v = n1;
      }
      float xv[8] = {u.x, u.y, u.z, u.w, v.x, v.y, v.z, v.w};
      #pragma unroll
      for (int i = 0; i < 8; ++i) {
        _Float16 h = (_Float16)xv[i];
        ah[kc][i] = h; al[kc][i] = (_Float16)(xv[i] - (float)h);
      }
    }
  }

  float rv1[4], rv2[4]; int ri1[4];
  #pragma unroll
  for (int r = 0; r < 4; ++r) { rv1[r] = 3.0e38f; rv2[r] = 3.0e38f; ri1[r] = 0x7fffffff; }

#define STAGE_B(BUF, NT, KCB_)                                               \
  { _Pragma("unroll")                                                        \
    for (int cc = 0; cc < 8; ++cc) {                                         \
      int p = cc * 4 + w;                                                    \
      int half = p & 1, ni = (p >> 1) & 7, kcw = p >> 4;                     \
      const f16x8* src =                                                     \
          &EfC[(((size_t)(NT) * 8 + ni) * 16 + (KCB_) + kcw + (half ? 8 : 0))\
               * 64 + lane];                                                 \
      __builtin_amdgcn_global_load_lds(                                      \
          (const __attribute__((address_space(1))) uint32_t*)src,            \
          (__attribute__((address_space(3))) uint32_t*)&ldsB[BUF][kcw][ni][half][0], \
          16, 0, 0);                                                         \
    } }

#define MFMA_CHUNK(BUF, KCB_)                                                \
  { _Pragma("unroll")                                                        \
    for (int kcw = 0; kcw < 2; ++kcw) {                                      \
      _Pragma("unroll")                                                      \
      for (int ni = 0; ni < 8; ++ni) {                                       \
        f16x8 bh = ldsB[BUF][kcw][ni][0][lane];                              \
        f16x8 bl = ldsB[BUF][kcw][ni][1][lane];                              \
        acc[ni] = __builtin_amdgcn_mfma_f32_16x16x32_f16(                    \
            ah[(KCB_) + kcw], bh, acc[ni], 0, 0, 0);                         \
        acc[ni] = __builtin_amdgcn_mfma_f32_16x16x32_f16(                    \
            al[(KCB_) + kcw], bh, acc[ni], 0, 0, 0);                         \
        acc[ni] = __builtin_amdgcn_mfma_f32_16x16x32_f16(                    \
            ah[(KCB_) + kcw], bl, acc[ni], 0, 0, 0);                         \
      }                                                                      \
    } }

  f32x4 acc[8];
  #pragma unroll
  for (int ni = 0; ni < 8; ++ni) acc[ni] = (f32x4){0.f, 0.f, 0.f, 0.f};

  STAGE_B(0, 0, 0)
  __syncthreads();

  #pragma unroll 1
  for (int ntile = 0; ntile < 8; ++ntile) {
    #pragma unroll
    for (int chunk = 0; chunk < 4; ++chunk) {       // kcb = chunk*2, static
      const int buf = chunk & 1;                    // ntile*4 even -> parity static
      if (ntile * 4 + chunk < 31) {
        int nt2  = (chunk < 3) ? ntile : ntile + 1;
        int kcb2 = ((chunk + 1) & 3) * 2;
        STAGE_B(buf ^ 1, nt2, kcb2)
      }
      MFMA_CHUNK(buf, chunk * 2)
      __syncthreads();
    }
    // ---- epilogue for this ntile: best/second over 128 ks, merge running ----
    const int n0 = ntile * 128;
    float se[8];
    #pragma unroll
    for (int ni = 0; ni < 8; ++ni) se[ni] = sume[n0 + ni * 16 + (lane & 15)];
    #pragma unroll
    for (int r = 0; r < 4; ++r) {
      float v1 = 3.0e38f, v2 = 3.0e38f; int i1 = 0x7fffffff;
      #pragma unroll
      for (int ni = 0; ni < 8; ++ni) {
        float key = fmaf(-2.0f, acc[ni][r], se[ni]);
        int   k   = n0 + ni * 16 + (lane & 15);
        if (key < v1 || (key == v1 && k < i1)) { v2 = v1; v1 = key; i1 = k; }
        else { v2 = fminf(v2, key); }
      }
      #pragma unroll
      for (int off = 1; off < 16; off <<= 1) {
        float ov1 = __shfl_xor(v1, off, 64);
        int   oi1 = __shfl_xor(i1, off, 64);
        float ov2 = __shfl_xor(v2, off, 64);
        if (ov1 < v1 || (ov1 == v1 && oi1 < i1)) { v2 = fminf(ov2, v1); v1 = ov1; i1 = oi1; }
        else { v2 = fminf(v2, fminf(ov1, ov2)); }
      }
      if (v1 < rv1[r] || (v1 == rv1[r] && i1 < ri1[r])) {
        rv2[r] = fminf(rv1[r], v2); rv1[r] = v1; ri1[r] = i1;
      } else { rv2[r] = fminf(rv2[r], fminf(v1, v2)); }
    }
    #pragma unroll
    for (int ni = 0; ni < 8; ++ni) acc[ni] = (f32x4){0.f, 0.f, 0.f, 0.f};
  }
#undef STAGE_B
#undef MFMA_CHUNK

  if ((lane & 15) == 0) {
    #pragma unroll
    for (int r = 0; r < 4; ++r) {
      int token = m0w + (lane >> 4) * 4 + r;
      idx_ws[token] = ri1[r];
      if (rv2[r] - rv1[r] < EPS_GAP) {
        int pos = atomicAdd(fix_cnt, 1);
        fix_list[pos] = token;
      }
      int b = token >> 11, n = token & (NTOK - 1);
      idxf[(size_t)b * (CBOOKS * NTOK) + n] = (float)ri1[r];
    }
  }
}

// ---------------------------------------------------------------------------
// Exact numpy rescan (r14-verified) + FUSED: zero next pass's counter and
// prepack next codebook (blocks 0..15, after the fixup loop).
// ---------------------------------------------------------------------------
__global__ __launch_bounds__(256, 2) void rvq_fixup_kernel(
    const float* __restrict__ xr, const float* __restrict__ cbc,
    const float* __restrict__ sume, const int* __restrict__ fix_list,
    const int* __restrict__ fix_cnt, int* __restrict__ idx_ws,
    float* __restrict__ idxf, const float* __restrict__ cbn,
    f16x8* __restrict__ EfC, int* __restrict__ fix_cnt_nxt, int prepack) {
  #pragma clang fp contract(off)
  __shared__ float xs[DIM];
  __shared__ float redv[4];
  __shared__ int   redi[4];
  __shared__ float sxv_sh;
  const int tid  = threadIdx.x;
  const int nfix = *fix_cnt;

  if (blockIdx.x == 0 && tid == 0) *fix_cnt_nxt = 0;

  #pragma unroll 1
  for (int i = blockIdx.x; i < nfix; i += gridDim.x) {
    int token = fix_list[i];
    __syncthreads();                           // xs reuse guard
    if (tid < 64)
      ((float4*)xs)[tid] = ((const float4*)xr)[(size_t)token * 64 + tid];
    __syncthreads();
    if (tid < 64) {
      float s = 0.f;
      if ((tid & 63) < 16) {
        int j = tid & 7, hh = (tid >> 3) & 1;
        const float* bb = xs + hh * 128;
        float r = bb[j] * bb[j];
        #pragma unroll 1
        for (int t = 1; t < 16; ++t) r = r + bb[8 * t + j] * bb[8 * t + j];
        s = r;
      }
      #pragma unroll
      for (int off = 1; off <= 8; off <<= 1)
        s = s + __shfl_xor(s, off, 64);        // commutative pairs -> exact tree
      if (tid == 0) sxv_sh = s;
    }
    __syncthreads();
    float sxv = sxv_sh;
    float bv = 3.0e38f; int bi = 0x7fffffff;
    #pragma unroll 1
    for (int kk = 0; kk < 4; ++kk) {
      int k = kk * 256 + tid;
      float4 vacc = {0.f, 0.f, 0.f, 0.f};
      #pragma unroll 1
      for (int t = 0; t < 16; ++t) {
        float4 ab = vacc;
        #pragma unroll
        for (int j = 3; j >= 0; --j) {         // reverse-chained npyv block
          float4 xq = *(const float4*)&xs[t * 16 + j * 4];
          float4 eq = *(const float4*)&cbc[(size_t)k * DIM + t * 16 + j * 4];
          ab = f4_muladd(xq, eq, ab);
        }
        vacc = ab;
      }
      float dot = (vacc.x + vacc.y) + (vacc.z + vacc.w);
      float d2  = (sxv - 2.0f * dot) + sume[k];
      if (d2 < bv || (d2 == bv && k < bi)) { bv = d2; bi = k; }
    }
    #pragma unroll
    for (int off = 1; off < 64; off <<= 1) {
      float ov = __shfl_xor(bv, off, 64);
      int   oi = __shfl_xor(bi, off, 64);
      if (ov < bv || (ov == bv && oi < bi)) { bv = ov; bi = oi; }
    }
    int w = tid >> 6;
    if ((tid & 63) == 0) { redv[w] = bv; redi[w] = bi; }
    __syncthreads();
    if (tid == 0) {
      #pragma unroll
      for (int ww = 1; ww < 4; ++ww)
        if (redv[ww] < bv || (redv[ww] == bv && redi[ww] < bi)) { bv = redv[ww]; bi = redi[ww]; }
      idx_ws[token] = bi;
      int b = token >> 11, n = token & (NTOK - 1);
      idxf[(size_t)b * (CBOOKS * NTOK) + n] = (float)bi;
    }
  }

  // fused prepack of next codebook (EfC not read until next screen launch)
  if (prepack && blockIdx.x < 16) {
    prepack_cb(cbn, EfC, blockIdx.x * 4 + (tid >> 6), tid & 63);
  }
}

// Final-pass update only (r7-verified fp order): zq_out = zq + zi.
__global__ __launch_bounds__(256) void rvq_zq_final_kernel(
    const float* __restrict__ xsrc, const float* __restrict__ cbc,
    const int* __restrict__ idx_ws, float* __restrict__ zq) {
  #pragma clang fp contract(off)
  int gid   = blockIdx.x * 256 + threadIdx.x;
  int token = gid >> 6;
  int q     = gid & 63;
  int idx   = idx_ws[token];
  float4 e = ((const float4*)cbc)[(size_t)idx * 64 + q];
  float4 x = ((const float4*)xsrc)[gid];
  float4 zi;
  zi.x = x.x + (e.x - x.x); zi.y = x.y + (e.y - x.y);
  zi.z = x.z + (e.z - x.z); zi.w = x.w + (e.w - x.w);
  float4 z = ((float4*)zq)[gid];
  float4 zo;
  zo.x = z.x + zi.x; zo.y = z.y + zi.y; zo.z = z.z + zi.z; zo.w = z.w + zi.w;
  ((float4*)zq)[gid] = zo;
}

// ---------------------------------------------------------------------------
extern "C" void kernel_launch(void* const* d_in, const int* in_sizes, int n_in,
                              void* d_out, int out_size, void* d_ws, size_t ws_size,
                              hipStream_t stream) {
  const float* x_in = (const float*)d_in[0];
  const float* cbs  = (const float*)d_in[1];
  float* zq      = (float*)d_out;
  float* idxbase = (float*)d_out + ZQ_ELEMS;

  // proven 40 MB footprint (r7..r25)
  char* ws = (char*)d_ws;
  float*  sume     = (float*)ws;                     // 32 KB
  int*    idx_ws   = (int*)(ws + (256 << 10));       // 128 KB
  int*    fix_list = (int*)(ws + (448 << 10));       // 128 KB
  int*    fix_cnt2 = (int*)(ws + (640 << 10));       // 8 B (double-buffered)
  f16x8*  EfC      = (f16x8*)(ws + (5 << 20));       // 1 MB (hi+lo)
  float*  xr       = (float*)(ws + (8 << 20));       // 32 MB -> ends 40 MB

  rvq_norms_kernel<<<32, 256, 0, stream>>>(cbs, sume, EfC, fix_cnt2);
  for (int c = 0; c < CBOOKS; ++c) {
    const float* xsrc = (c <= 1) ? x_in : xr;
    const float* cbp  = cbs + (size_t)(c > 0 ? c - 1 : 0) * KCB * DIM;
    const float* cbc  = cbs + (size_t)c * KCB * DIM;
    const float* cbn  = cbs + (size_t)((c + 1 < CBOOKS) ? c + 1 : c) * KCB * DIM;
    float* idxf = idxbase + (size_t)c * NTOK;
    int mode = (c == 0) ? 0 : (c == 1) ? 1 : 2;
    int* cnt_cur = fix_cnt2 + (c & 1);
    int* cnt_nxt = fix_cnt2 + ((c + 1) & 1);
    rvq_screen_kernel<<<512, 256, 0, stream>>>(
        xsrc, cbp, EfC, sume + (size_t)c * KCB, idx_ws, fix_list, cnt_cur,
        idxf, zq, xr, mode);
    rvq_fixup_kernel<<<256, 256, 0, stream>>>(
        (c == 0) ? x_in : xr, cbc, sume + (size_t)c * KCB,
        fix_list, cnt_cur, idx_ws, idxf,
        cbn, EfC, cnt_nxt, (c + 1 < CBOOKS) ? 1 : 0);
  }
  // final pass-7 update: zq += zi_7 (reads r_7 = xr, idx_7)
  rvq_zq_final_kernel<<<8192, 256, 0, stream>>>(
      xr, cbs + (size_t)(CBOOKS - 1) * KCB * DIM, idx_ws, zq);
}